// Round 1
// baseline (5180.976 us; speedup 1.0000x reference)
//
#include <hip/hip_runtime.h>
#include <math.h>

#ifndef M_PI
#define M_PI 3.14159265358979323846
#endif

#define MATS 8
#define BLK 192           // MATS*24 threads; thread tile = 2 rows x 12 cols
#define NMATS 38400
#define NGROUPS 1536
#define LROW 588          // per-buffer stride in floats (24*24 + 12)

static_assert(BLK == MATS * 24, "block = MATS*24");

struct Coefs { float c[32]; };

// ---------- vector helpers (all fully unrolled; no dynamic reg indexing) ----------
__device__ __forceinline__ void ld12(const float* p, float* r) {
  const float4* q = (const float4*)p;
#pragma unroll
  for (int i = 0; i < 3; ++i) {
    float4 v = q[i];
    r[4*i+0] = v.x; r[4*i+1] = v.y; r[4*i+2] = v.z; r[4*i+3] = v.w;
  }
}
__device__ __forceinline__ void st12(float* p, const float* r) {
  float4* q = (float4*)p;
#pragma unroll
  for (int i = 0; i < 3; ++i)
    q[i] = make_float4(r[4*i+0], r[4*i+1], r[4*i+2], r[4*i+3]);
}
__device__ __forceinline__ void ld24(const float* p, float* r) {
  const float4* q = (const float4*)p;
#pragma unroll
  for (int i = 0; i < 6; ++i) {
    float4 v = q[i];
    r[4*i+0] = v.x; r[4*i+1] = v.y; r[4*i+2] = v.z; r[4*i+3] = v.w;
  }
}
__device__ __forceinline__ void zero12(float* r) {
#pragma unroll
  for (int j = 0; j < 12; ++j) r[j] = 0.f;
}
// += c on the diagonal elements that land in this thread's 2x12 tile
__device__ __forceinline__ void add_diag(float* t0, float* t1, int p, int h, float c) {
#pragma unroll
  for (int j = 0; j < 12; ++j) {
    t0[j] += (h == 0 && j == p) ? c : 0.f;
    t1[j] += (h == 1 && j == p) ? c : 0.f;
  }
}

// acc{0,1}[j] += sum_k a{0,1}[k] * B[k*24 + j], j over this thread's 12-col slice.
// B points at (LDS buffer + c0). k-loop fully unrolled so a0[k]/a1[k] are static;
// sched_barrier every 6 steps bounds load hoisting (<=18 ds_reads in flight).
__device__ __forceinline__ void mmtile(const float* __restrict__ a0,
                                       const float* __restrict__ a1,
                                       const float* __restrict__ B,
                                       float* __restrict__ acc0,
                                       float* __restrict__ acc1) {
#pragma unroll
  for (int k = 0; k < 24; ++k) {
    float b[12];
    ld12(B + k*24, b);
    const float x0 = a0[k], x1 = a1[k];
#pragma unroll
    for (int j = 0; j < 12; ++j) { acc0[j] += x0 * b[j]; acc1[j] += x1 * b[j]; }
    if ((k % 6) == 5) __builtin_amdgcn_sched_barrier(0);
  }
}

// partner-lane (lane^1) copies of a 12-wide tile; partner == (p, h^1) of the
// same matrix because tid = lm*24 + t24 with 24 even => lane^1 flips h only.
__device__ __forceinline__ void pswap12(const float* __restrict__ src,
                                        float* __restrict__ dst) {
#pragma unroll
  for (int j = 0; j < 12; ++j) dst[j] = __shfl_xor(src[j], 1, 64);
}

// Same as mmtile, but the A-operand rows are assembled from registers:
// own tile A0/A1 holds cols c0..c0+11 of rows p,p+12; PA0/PA1 (from pswap12)
// holds the partner's cols (c0^12)..(c0^12)+11. Placement resolved per static k
// with one cndmask. Accumulation order identical to mmtile (bitwise match).
__device__ __forceinline__ void mmtile_r(const float* __restrict__ A0,
                                         const float* __restrict__ A1,
                                         const float* __restrict__ PA0,
                                         const float* __restrict__ PA1,
                                         const int h,
                                         const float* __restrict__ B,
                                         float* __restrict__ acc0,
                                         float* __restrict__ acc1) {
#pragma unroll
  for (int k = 0; k < 24; ++k) {
    float b[12];
    ld12(B + k*24, b);
    float x0, x1;
    if (k < 12) {
      x0 = h ? PA0[k] : A0[k];
      x1 = h ? PA1[k] : A1[k];
    } else {
      x0 = h ? A0[k-12] : PA0[k-12];
      x1 = h ? A1[k-12] : PA1[k-12];
    }
#pragma unroll
    for (int j = 0; j < 12; ++j) { acc0[j] += x0 * b[j]; acc1[j] += x1 * b[j]; }
    if ((k % 6) == 5) __builtin_amdgcn_sched_barrier(0);
  }
}

// ---------- K1: logm, degree-23 Chebyshev->monomial, PS k=4 ----------
__global__ __launch_bounds__(BLK) void k_logm(const float* __restrict__ x,
                                              float* __restrict__ out, Coefs cf) {
  __shared__ __align__(16) float lds[MATS][4][LROW];   // 75264 B -> 2 blocks/CU
  const int tid = threadIdx.x;
  const int lm = tid / 24, t24 = tid % 24, p = t24 >> 1, h = t24 & 1, c0 = h * 12;
  const long mat = (long)blockIdx.x * MATS + lm;
  float *L0 = lds[lm][0], *L1 = lds[lm][1], *L2 = lds[lm][2], *L3 = lds[lm][3];
  const float invd = cf.c[30], cd = cf.c[31];

  float u0[12], u1[12];
  ld12(x + mat*576 + p*24 + c0, u0);
  ld12(x + mat*576 + (p+12)*24 + c0, u1);
#pragma unroll
  for (int j = 0; j < 12; ++j) { u0[j] *= invd; u1[j] *= invd; }
  add_diag(u0, u1, p, h, -cd);
  st12(&L0[p*24 + c0], u0); st12(&L0[(p+12)*24 + c0], u1);
  __syncthreads();

  float a0[24], a1[24], t0[12], t1[12];
  // u2 -> L1
  ld24(&L0[p*24], a0); ld24(&L0[(p+12)*24], a1);
  zero12(t0); zero12(t1);
  mmtile(a0, a1, L0 + c0, t0, t1);
  st12(&L1[p*24 + c0], t0); st12(&L1[(p+12)*24 + c0], t1);
  __syncthreads();
  // u3 -> L2
  ld24(&L1[p*24], a0); ld24(&L1[(p+12)*24], a1);
  zero12(t0); zero12(t1);
  mmtile(a0, a1, L0 + c0, t0, t1);
  st12(&L2[p*24 + c0], t0); st12(&L2[(p+12)*24 + c0], t1);
  __syncthreads();
  // u4 -> (regs), then overwrite L0
  ld24(&L2[p*24], a0); ld24(&L2[(p+12)*24], a1);
  zero12(t0); zero12(t1);
  mmtile(a0, a1, L0 + c0, t0, t1);
  __syncthreads();                       // all reads of L0(=u) done
  st12(&L0[p*24 + c0], t0); st12(&L0[(p+12)*24 + c0], t1);
  __syncthreads();                       // L0 = u4 visible

  // top PS block jb=5: c20 I + c21 u + c22 u2 + c23 u3
  float P0[12], P1[12], w0[12], w1[12];
  ld12(&L1[p*24 + c0], w0); ld12(&L1[(p+12)*24 + c0], w1);
#pragma unroll
  for (int j = 0; j < 12; ++j) {
    P0[j] = cf.c[21]*u0[j] + cf.c[22]*w0[j];
    P1[j] = cf.c[21]*u1[j] + cf.c[22]*w1[j];
  }
  ld12(&L2[p*24 + c0], w0); ld12(&L2[(p+12)*24 + c0], w1);
#pragma unroll
  for (int j = 0; j < 12; ++j) { P0[j] += cf.c[23]*w0[j]; P1[j] += cf.c[23]*w1[j]; }
  add_diag(P0, P1, p, h, cf.c[20]);

#pragma unroll 1
  for (int jb = 4; jb >= 0; --jb) {
    st12(&L3[p*24 + c0], P0); st12(&L3[(p+12)*24 + c0], P1);
    __syncthreads();
    float acc0[12], acc1[12];
    ld12(&L1[p*24 + c0], w0); ld12(&L1[(p+12)*24 + c0], w1);
#pragma unroll
    for (int j = 0; j < 12; ++j) {
      acc0[j] = cf.c[4*jb+1]*u0[j] + cf.c[4*jb+2]*w0[j];
      acc1[j] = cf.c[4*jb+1]*u1[j] + cf.c[4*jb+2]*w1[j];
    }
    ld12(&L2[p*24 + c0], w0); ld12(&L2[(p+12)*24 + c0], w1);
#pragma unroll
    for (int j = 0; j < 12; ++j) { acc0[j] += cf.c[4*jb+3]*w0[j]; acc1[j] += cf.c[4*jb+3]*w1[j]; }
    add_diag(acc0, acc1, p, h, cf.c[4*jb]);
    ld24(&L3[p*24], a0); ld24(&L3[(p+12)*24], a1);
    mmtile(a0, a1, L0 + c0, acc0, acc1);   // += P * u4
#pragma unroll
    for (int j = 0; j < 12; ++j) { P0[j] = acc0[j]; P1[j] = acc1[j]; }
    __syncthreads();                       // L3 reads done before next overwrite
  }
  st12(out + mat*576 + p*24 + c0, P0);
  st12(out + mat*576 + (p+12)*24 + c0, P1);
}

// ---------- K2: graph aggregation (unchanged structure) ----------
__global__ __launch_bounds__(256) void k_agg(const float* __restrict__ A,
                                             float* __restrict__ io) {
  __shared__ __align__(16) float Lg[25*576];
  __shared__ float Ag[625];
  const int g = blockIdx.x;
  const float* Lbase = io + (long)g * 25 * 576;
  for (int i = threadIdx.x; i < 25*576/4; i += 256)
    ((float4*)Lg)[i] = ((const float4*)Lbase)[i];
  for (int i = threadIdx.x; i < 625; i += 256)
    Ag[i] = A[(long)g*625 + i];
  __syncthreads();
  for (int rr = threadIdx.x; rr < 600; rr += 256) {
    const int r = rr / 25, j = rr % 25;
    float acc[24];
#pragma unroll
    for (int q = 0; q < 24; ++q) acc[q] = 0.f;
#pragma unroll 1
    for (int v = 0; v < 25; ++v) {
      const float a = Ag[v*25 + j];
      float b[24];
      ld24(&Lg[v*576 + r*24], b);
#pragma unroll
      for (int q = 0; q < 24; ++q) acc[q] += a * b[q];
    }
    float* dst = io + ((long)g*25 + j)*576 + (long)r*24;
    float4* qd = (float4*)dst;
#pragma unroll
    for (int i = 0; i < 6; ++i)
      qd[i] = make_float4(acc[4*i], acc[4*i+1], acc[4*i+2], acc[4*i+3]);
  }
}

// ---------- K3: expm, degree-11 Chebyshev->monomial, PS k=3, in place ----------
__global__ __launch_bounds__(BLK) void k_expm(float* __restrict__ io, Coefs cf) {
  __shared__ __align__(16) float lds[MATS][3][LROW];   // 56448 B
  const int tid = threadIdx.x;
  const int lm = tid / 24, t24 = tid % 24, p = t24 >> 1, h = t24 & 1, c0 = h * 12;
  const long mat = (long)blockIdx.x * MATS + lm;
  float *L0 = lds[lm][0], *L1 = lds[lm][1], *L2 = lds[lm][2];
  const float invd = cf.c[30], cd = cf.c[31];

  float u0[12], u1[12];
  ld12(io + mat*576 + p*24 + c0, u0);
  ld12(io + mat*576 + (p+12)*24 + c0, u1);
#pragma unroll
  for (int j = 0; j < 12; ++j) { u0[j] *= invd; u1[j] *= invd; }
  add_diag(u0, u1, p, h, -cd);
  st12(&L0[p*24 + c0], u0); st12(&L0[(p+12)*24 + c0], u1);
  __syncthreads();

  float a0[24], a1[24], t0[12], t1[12];
  // u2 -> L1
  ld24(&L0[p*24], a0); ld24(&L0[(p+12)*24], a1);
  zero12(t0); zero12(t1);
  mmtile(a0, a1, L0 + c0, t0, t1);
  st12(&L1[p*24 + c0], t0); st12(&L1[(p+12)*24 + c0], t1);
  __syncthreads();
  // u3 -> regs, overwrite L0
  ld24(&L1[p*24], a0); ld24(&L1[(p+12)*24], a1);
  zero12(t0); zero12(t1);
  mmtile(a0, a1, L0 + c0, t0, t1);
  __syncthreads();
  st12(&L0[p*24 + c0], t0); st12(&L0[(p+12)*24 + c0], t1);
  __syncthreads();                       // L0 = u3

  float w0[12], w1[12];
  ld12(&L1[p*24 + c0], w0); ld12(&L1[(p+12)*24 + c0], w1);   // u2 tiles (persistent)
  float P0[12], P1[12];
#pragma unroll
  for (int j = 0; j < 12; ++j) {
    P0[j] = cf.c[10]*u0[j] + cf.c[11]*w0[j];
    P1[j] = cf.c[10]*u1[j] + cf.c[11]*w1[j];
  }
  add_diag(P0, P1, p, h, cf.c[9]);

#pragma unroll 1
  for (int jb = 2; jb >= 0; --jb) {
    st12(&L2[p*24 + c0], P0); st12(&L2[(p+12)*24 + c0], P1);
    __syncthreads();
    float acc0[12], acc1[12];
#pragma unroll
    for (int j = 0; j < 12; ++j) {
      acc0[j] = cf.c[3*jb+1]*u0[j] + cf.c[3*jb+2]*w0[j];
      acc1[j] = cf.c[3*jb+1]*u1[j] + cf.c[3*jb+2]*w1[j];
    }
    add_diag(acc0, acc1, p, h, cf.c[3*jb]);
    ld24(&L2[p*24], a0); ld24(&L2[(p+12)*24], a1);
    mmtile(a0, a1, L0 + c0, acc0, acc1);   // += P * u3
#pragma unroll
    for (int j = 0; j < 12; ++j) { P0[j] = acc0[j]; P1[j] = acc1[j]; }
    __syncthreads();
  }
  st12(io + mat*576 + p*24 + c0, P0);
  st12(io + mat*576 + (p+12)*24 + c0, P1);
}

// ---------- K4: congruence + Frobenius norm + 9-step Newton-Schulz sqrt ----------
// Rewritten: only the shared B-operand (M) lives in LDS (one buffer/mat).
// A-operand rows are assembled in registers via lane^1 shuffles, eliminating
// the LY/LT buffers, the A-operand LDS round-trips, and half the barriers.
// LDS 59904 -> ~21.9 KB: occupancy 2 -> 4 blocks/CU (VGPR-capped at 3 waves/EU).
// Arithmetic order is bitwise-identical to the previous version.
__global__ __launch_bounds__(BLK, 3) void k_csqrt(float* __restrict__ io,
                                                  const float* __restrict__ W) {
  __shared__ __align__(16) float lds[MATS][LROW];     // 18816 B (B-operand only)
  __shared__ __align__(16) float Wt[576];
  __shared__ float red[BLK];
  const int tid = threadIdx.x;
  const int lm = tid / 24, t24 = tid % 24, p = t24 >> 1, h = t24 & 1, c0 = h * 12;
  const long mat = (long)blockIdx.x * MATS + lm;
  float* LB = lds[lm];

  for (int i = tid; i < 576; i += BLK) {
    const int k = i / 24, j = i % 24;
    Wt[i] = W[j*24 + k];
  }
  {
    float e0[12], e1[12];
    ld12(io + mat*576 + p*24 + c0, e0);
    ld12(io + mat*576 + (p+12)*24 + c0, e1);
    st12(&LB[p*24 + c0], e0); st12(&LB[(p+12)*24 + c0], e1);
  }
  float a0[24], a1[24];
  ld24(W + p*24, a0); ld24(W + (p+12)*24, a1);    // W rows (A-operand, from global)
  __syncthreads();

  // F = W * E  (tiles stay in registers)
  float f0[12], f1[12];
  zero12(f0); zero12(f1);
  mmtile(a0, a1, LB + c0, f0, f1);

  // C = F * W^T  (A = F rows via shuffle)
  float ct0[12], ct1[12];
  zero12(ct0); zero12(ct1);
  {
    float pf0[12], pf1[12];
    pswap12(f0, pf0); pswap12(f1, pf1);
    mmtile_r(f0, f1, pf0, pf1, h, Wt + c0, ct0, ct1);
  }
  float s = 0.f;
#pragma unroll
  for (int j = 0; j < 12; ++j) s += ct0[j]*ct0[j] + ct1[j]*ct1[j];
  red[tid] = s;
  __syncthreads();                                // also: all LB(E) reads done
  float tot = 0.f;
#pragma unroll
  for (int q = 0; q < 24; ++q) tot += red[lm*24 + q];
  const float inv = 1.0f / sqrtf(tot);

  float Y0[12], Y1[12], M0[12], M1[12];
#pragma unroll
  for (int j = 0; j < 12; ++j) { M0[j] = ct0[j]*inv; M1[j] = ct1[j]*inv; }
  st12(&LB[p*24 + c0], M0); st12(&LB[(p+12)*24 + c0], M1);
  __syncthreads();                                // LB = M0 (normalized)

  // ---- iter 0 (a=2, Y=M): Y1 = 2M - M*M ; M1 = (M*T)*T
  {
    float mm0[12], mm1[12];
    zero12(mm0); zero12(mm1);
    {
      float pm0[12], pm1[12];
      pswap12(M0, pm0); pswap12(M1, pm1);
      mmtile_r(M0, M1, pm0, pm1, h, LB + c0, mm0, mm1);   // M*M
    }
#pragma unroll
    for (int j = 0; j < 12; ++j) {
      Y0[j] = 2.f*M0[j] - mm0[j];                 // MT tiles (= new Y)
      Y1[j] = 2.f*M1[j] - mm1[j];
    }
    float q0[12], q1[12];
    zero12(q0); zero12(q1);
    {
      float py0[12], py1[12];
      pswap12(Y0, py0); pswap12(Y1, py1);
      mmtile_r(Y0, Y1, py0, py1, h, LB + c0, q0, q1);     // (MT)*M
    }
#pragma unroll
    for (int j = 0; j < 12; ++j) {
      M0[j] = 2.f*Y0[j] - q0[j];                  // newM = 2*MT - MT*M
      M1[j] = 2.f*Y1[j] - q1[j];
    }
    __syncthreads();                              // all LB reads done
    st12(&LB[p*24 + c0], M0); st12(&LB[(p+12)*24 + c0], M1);
    __syncthreads();
  }

  // ---- iters 1..7
#pragma unroll 1
  for (int it = 1; it < 8; ++it) {
    const float aa = (it < 6) ? 2.0f : 1.5f;
    const float am1 = aa - 1.0f;
    float ym0[12], ym1[12];
    zero12(ym0); zero12(ym1);
    {
      float py0[12], py1[12];
      pswap12(Y0, py0); pswap12(Y1, py1);
      mmtile_r(Y0, Y1, py0, py1, h, LB + c0, ym0, ym1);   // Y*M
    }
    float mm0[12], mm1[12];
    zero12(mm0); zero12(mm1);
    {
      float pm0[12], pm1[12];
      pswap12(M0, pm0); pswap12(M1, pm1);
      mmtile_r(M0, M1, pm0, pm1, h, LB + c0, mm0, mm1);   // M*M
    }
#pragma unroll
    for (int j = 0; j < 12; ++j) {
      Y0[j] = aa*Y0[j] - am1*ym0[j];              // newY = Y*T
      Y1[j] = aa*Y1[j] - am1*ym1[j];
      mm0[j] = aa*M0[j] - am1*mm0[j];             // MT = M*T
      mm1[j] = aa*M1[j] - am1*mm1[j];
    }
    float q0[12], q1[12];
    zero12(q0); zero12(q1);
    {
      float pt0[12], pt1[12];
      pswap12(mm0, pt0); pswap12(mm1, pt1);
      mmtile_r(mm0, mm1, pt0, pt1, h, LB + c0, q0, q1);   // (MT)*M
    }
#pragma unroll
    for (int j = 0; j < 12; ++j) {
      M0[j] = aa*mm0[j] - am1*q0[j];              // newM = MT*T
      M1[j] = aa*mm1[j] - am1*q1[j];
    }
    __syncthreads();                              // all LB reads done
    st12(&LB[p*24 + c0], M0); st12(&LB[(p+12)*24 + c0], M1);
    __syncthreads();
  }

  // ---- iter 8 (a=1.5): final Y = 1.5*Y - 0.5*(Y*M)
  {
    float ym0[12], ym1[12];
    zero12(ym0); zero12(ym1);
    float py0[12], py1[12];
    pswap12(Y0, py0); pswap12(Y1, py1);
    mmtile_r(Y0, Y1, py0, py1, h, LB + c0, ym0, ym1);
#pragma unroll
    for (int j = 0; j < 12; ++j) {
      Y0[j] = 1.5f*Y0[j] - 0.5f*ym0[j];
      Y1[j] = 1.5f*Y1[j] - 0.5f*ym1[j];
    }
  }
  st12(io + mat*576 + p*24 + c0, Y0);
  st12(io + mat*576 + (p+12)*24 + c0, Y1);
}

// ---------- host: Chebyshev interpolation -> monomial coefficients in u ----------
static void chebfit_host(double lo, double hi, int D, int islog, float* out) {
  const int N = 200;
  double a[32];
  for (int k = 0; k < 32; ++k) a[k] = 0.0;
  for (int i = 0; i < N; ++i) {
    double th = M_PI * (i + 0.5) / N;
    double u = cos(th);
    double xx = 0.5 * ((hi - lo) * u + (hi + lo));
    double f = islog ? log(xx) : exp(xx);
    for (int k = 0; k <= D; ++k) a[k] += f * cos(k * th);
  }
  for (int k = 0; k <= D; ++k) a[k] *= 2.0 / N;
  a[0] *= 0.5;
  double b[32], tp[32], tc[32], tn[32];
  for (int m = 0; m < 32; ++m) { b[m] = 0; tp[m] = 0; tc[m] = 0; tn[m] = 0; }
  tp[0] = 1.0; b[0] += a[0];
  tc[1] = 1.0; if (D >= 1) b[1] += a[1];
  for (int k = 2; k <= D; ++k) {
    for (int m = 0; m < 32; ++m) tn[m] = -tp[m];
    for (int m = 1; m < 32; ++m) tn[m] += 2.0 * tc[m-1];
    for (int m = 0; m <= k; ++m) b[m] += a[k] * tn[m];
    for (int m = 0; m < 32; ++m) { tp[m] = tc[m]; tc[m] = tn[m]; }
  }
  for (int m = 0; m < 32; ++m) out[m] = (float)b[m];
  out[30] = (float)(2.0 / (hi - lo));          // 1/d
  out[31] = (float)((hi + lo) / (hi - lo));    // c/d
}

extern "C" void kernel_launch(void* const* d_in, const int* in_sizes, int n_in,
                              void* d_out, int out_size, void* d_ws, size_t ws_size,
                              hipStream_t stream) {
  const float* x = (const float*)d_in[0];
  const float* A = (const float*)d_in[1];
  const float* W = (const float*)d_in[2];
  float* out = (float*)d_out;

  Coefs cl, ce;
  chebfit_host(0.47, 7.9, 23, 1, cl.c);   // log on the SPD input spectrum
  chebfit_host(-1.8, 3.9, 11, 0, ce.c);   // exp on the aggregated tangent spectrum

  k_logm <<<NMATS/MATS, BLK, 0, stream>>>(x, out, cl);
  k_agg  <<<NGROUPS,   256, 0, stream>>>(A, out);
  k_expm <<<NMATS/MATS, BLK, 0, stream>>>(out, ce);
  k_csqrt<<<NMATS/MATS, BLK, 0, stream>>>(out, W);
}

// Round 5
// 1208.092 us; speedup vs baseline: 4.2886x; 4.2886x over previous
//
#include <hip/hip_runtime.h>
#include <math.h>

#ifndef M_PI
#define M_PI 3.14159265358979323846
#endif

#define MATS 8
#define BLK 192           // MATS*24 threads; thread tile = 2 rows x 12 cols
#define NMATS 38400
#define NGROUPS 1536
#define LROW 588          // per-buffer stride in floats (24*24 + 12)

static_assert(BLK == MATS * 24, "block = MATS*24");

struct Coefs { float c[32]; };

// ---------- vector helpers (all fully unrolled; no dynamic reg indexing) ----------
__device__ __forceinline__ void ld12(const float* p, float* r) {
  const float4* q = (const float4*)p;
#pragma unroll
  for (int i = 0; i < 3; ++i) {
    float4 v = q[i];
    r[4*i+0] = v.x; r[4*i+1] = v.y; r[4*i+2] = v.z; r[4*i+3] = v.w;
  }
}
__device__ __forceinline__ void st12(float* p, const float* r) {
  float4* q = (float4*)p;
#pragma unroll
  for (int i = 0; i < 3; ++i)
    q[i] = make_float4(r[4*i+0], r[4*i+1], r[4*i+2], r[4*i+3]);
}
__device__ __forceinline__ void ld24(const float* p, float* r) {
  const float4* q = (const float4*)p;
#pragma unroll
  for (int i = 0; i < 6; ++i) {
    float4 v = q[i];
    r[4*i+0] = v.x; r[4*i+1] = v.y; r[4*i+2] = v.z; r[4*i+3] = v.w;
  }
}
__device__ __forceinline__ void zero12(float* r) {
#pragma unroll
  for (int j = 0; j < 12; ++j) r[j] = 0.f;
}
// += c on the diagonal elements that land in this thread's 2x12 tile
__device__ __forceinline__ void add_diag(float* t0, float* t1, int p, int h, float c) {
#pragma unroll
  for (int j = 0; j < 12; ++j) {
    t0[j] += (h == 0 && j == p) ? c : 0.f;
    t1[j] += (h == 1 && j == p) ? c : 0.f;
  }
}

// acc{0,1}[j] += sum_k a{0,1}[k] * B[k*24 + j], j over this thread's 12-col slice.
// B points at (LDS buffer + c0). k-loop fully unrolled so a0[k]/a1[k] are static;
// sched_barrier every 6 steps bounds load hoisting (<=18 ds_reads in flight).
__device__ __forceinline__ void mmtile(const float* __restrict__ a0,
                                       const float* __restrict__ a1,
                                       const float* __restrict__ B,
                                       float* __restrict__ acc0,
                                       float* __restrict__ acc1) {
#pragma unroll
  for (int k = 0; k < 24; ++k) {
    float b[12];
    ld12(B + k*24, b);
    const float x0 = a0[k], x1 = a1[k];
#pragma unroll
    for (int j = 0; j < 12; ++j) { acc0[j] += x0 * b[j]; acc1[j] += x1 * b[j]; }
    if ((k % 6) == 5) __builtin_amdgcn_sched_barrier(0);
  }
}

// ---------- K1: logm, degree-23 Chebyshev->monomial, PS k=4 (unchanged) ----------
__global__ __launch_bounds__(BLK) void k_logm(const float* __restrict__ x,
                                              float* __restrict__ out, Coefs cf) {
  __shared__ __align__(16) float lds[MATS][4][LROW];   // 75264 B -> 2 blocks/CU
  const int tid = threadIdx.x;
  const int lm = tid / 24, t24 = tid % 24, p = t24 >> 1, h = t24 & 1, c0 = h * 12;
  const long mat = (long)blockIdx.x * MATS + lm;
  float *L0 = lds[lm][0], *L1 = lds[lm][1], *L2 = lds[lm][2], *L3 = lds[lm][3];
  const float invd = cf.c[30], cd = cf.c[31];

  float u0[12], u1[12];
  ld12(x + mat*576 + p*24 + c0, u0);
  ld12(x + mat*576 + (p+12)*24 + c0, u1);
#pragma unroll
  for (int j = 0; j < 12; ++j) { u0[j] *= invd; u1[j] *= invd; }
  add_diag(u0, u1, p, h, -cd);
  st12(&L0[p*24 + c0], u0); st12(&L0[(p+12)*24 + c0], u1);
  __syncthreads();

  float a0[24], a1[24], t0[12], t1[12];
  // u2 -> L1
  ld24(&L0[p*24], a0); ld24(&L0[(p+12)*24], a1);
  zero12(t0); zero12(t1);
  mmtile(a0, a1, L0 + c0, t0, t1);
  st12(&L1[p*24 + c0], t0); st12(&L1[(p+12)*24 + c0], t1);
  __syncthreads();
  // u3 -> L2
  ld24(&L1[p*24], a0); ld24(&L1[(p+12)*24], a1);
  zero12(t0); zero12(t1);
  mmtile(a0, a1, L0 + c0, t0, t1);
  st12(&L2[p*24 + c0], t0); st12(&L2[(p+12)*24 + c0], t1);
  __syncthreads();
  // u4 -> (regs), then overwrite L0
  ld24(&L2[p*24], a0); ld24(&L2[(p+12)*24], a1);
  zero12(t0); zero12(t1);
  mmtile(a0, a1, L0 + c0, t0, t1);
  __syncthreads();                       // all reads of L0(=u) done
  st12(&L0[p*24 + c0], t0); st12(&L0[(p+12)*24 + c0], t1);
  __syncthreads();                       // L0 = u4 visible

  // top PS block jb=5: c20 I + c21 u + c22 u2 + c23 u3
  float P0[12], P1[12], w0[12], w1[12];
  ld12(&L1[p*24 + c0], w0); ld12(&L1[(p+12)*24 + c0], w1);
#pragma unroll
  for (int j = 0; j < 12; ++j) {
    P0[j] = cf.c[21]*u0[j] + cf.c[22]*w0[j];
    P1[j] = cf.c[21]*u1[j] + cf.c[22]*w1[j];
  }
  ld12(&L2[p*24 + c0], w0); ld12(&L2[(p+12)*24 + c0], w1);
#pragma unroll
  for (int j = 0; j < 12; ++j) { P0[j] += cf.c[23]*w0[j]; P1[j] += cf.c[23]*w1[j]; }
  add_diag(P0, P1, p, h, cf.c[20]);

#pragma unroll 1
  for (int jb = 4; jb >= 0; --jb) {
    st12(&L3[p*24 + c0], P0); st12(&L3[(p+12)*24 + c0], P1);
    __syncthreads();
    float acc0[12], acc1[12];
    ld12(&L1[p*24 + c0], w0); ld12(&L1[(p+12)*24 + c0], w1);
#pragma unroll
    for (int j = 0; j < 12; ++j) {
      acc0[j] = cf.c[4*jb+1]*u0[j] + cf.c[4*jb+2]*w0[j];
      acc1[j] = cf.c[4*jb+1]*u1[j] + cf.c[4*jb+2]*w1[j];
    }
    ld12(&L2[p*24 + c0], w0); ld12(&L2[(p+12)*24 + c0], w1);
#pragma unroll
    for (int j = 0; j < 12; ++j) { acc0[j] += cf.c[4*jb+3]*w0[j]; acc1[j] += cf.c[4*jb+3]*w1[j]; }
    add_diag(acc0, acc1, p, h, cf.c[4*jb]);
    ld24(&L3[p*24], a0); ld24(&L3[(p+12)*24], a1);
    mmtile(a0, a1, L0 + c0, acc0, acc1);   // += P * u4
#pragma unroll
    for (int j = 0; j < 12; ++j) { P0[j] = acc0[j]; P1[j] = acc1[j]; }
    __syncthreads();                       // L3 reads done before next overwrite
  }
  st12(out + mat*576 + p*24 + c0, P0);
  st12(out + mat*576 + (p+12)*24 + c0, P1);
}

// ---------- K2: graph aggregation (unchanged structure) ----------
__global__ __launch_bounds__(256) void k_agg(const float* __restrict__ A,
                                             float* __restrict__ io) {
  __shared__ __align__(16) float Lg[25*576];
  __shared__ float Ag[625];
  const int g = blockIdx.x;
  const float* Lbase = io + (long)g * 25 * 576;
  for (int i = threadIdx.x; i < 25*576/4; i += 256)
    ((float4*)Lg)[i] = ((const float4*)Lbase)[i];
  for (int i = threadIdx.x; i < 625; i += 256)
    Ag[i] = A[(long)g*625 + i];
  __syncthreads();
  for (int rr = threadIdx.x; rr < 600; rr += 256) {
    const int r = rr / 25, j = rr % 25;
    float acc[24];
#pragma unroll
    for (int q = 0; q < 24; ++q) acc[q] = 0.f;
#pragma unroll 1
    for (int v = 0; v < 25; ++v) {
      const float a = Ag[v*25 + j];
      float b[24];
      ld24(&Lg[v*576 + r*24], b);
#pragma unroll
      for (int q = 0; q < 24; ++q) acc[q] += a * b[q];
    }
    float* dst = io + ((long)g*25 + j)*576 + (long)r*24;
    float4* qd = (float4*)dst;
#pragma unroll
    for (int i = 0; i < 6; ++i)
      qd[i] = make_float4(acc[4*i], acc[4*i+1], acc[4*i+2], acc[4*i+3]);
  }
}

// ---------- K3: expm, degree-11 Chebyshev->monomial, PS k=3, in place ----------
// 2 LDS buffers (was 3): u2-rows buffer is reused as the P scratch buffer;
// u2 tiles are kept in registers at production (bitwise-identical values to
// the old LDS re-read). 37632 B -> 4 blocks/CU (was 2).
__global__ __launch_bounds__(BLK) void k_expm(float* __restrict__ io, Coefs cf) {
  __shared__ __align__(16) float lds[MATS][2][LROW];   // 37632 B
  const int tid = threadIdx.x;
  const int lm = tid / 24, t24 = tid % 24, p = t24 >> 1, h = t24 & 1, c0 = h * 12;
  const long mat = (long)blockIdx.x * MATS + lm;
  float *La = lds[lm][0], *Lb = lds[lm][1];
  const float invd = cf.c[30], cd = cf.c[31];

  float u0[12], u1[12];
  ld12(io + mat*576 + p*24 + c0, u0);
  ld12(io + mat*576 + (p+12)*24 + c0, u1);
#pragma unroll
  for (int j = 0; j < 12; ++j) { u0[j] *= invd; u1[j] *= invd; }
  add_diag(u0, u1, p, h, -cd);
  st12(&La[p*24 + c0], u0); st12(&La[(p+12)*24 + c0], u1);
  __syncthreads();                       // La = u

  float a0[24], a1[24], t0[12], t1[12];
  // u2 tiles -> regs (w) and -> Lb (rows needed once for u3)
  ld24(&La[p*24], a0); ld24(&La[(p+12)*24], a1);
  zero12(t0); zero12(t1);
  mmtile(a0, a1, La + c0, t0, t1);
  float w0[12], w1[12];
#pragma unroll
  for (int j = 0; j < 12; ++j) { w0[j] = t0[j]; w1[j] = t1[j]; }   // u2 tiles (persistent)
  st12(&Lb[p*24 + c0], t0); st12(&Lb[(p+12)*24 + c0], t1);
  __syncthreads();                       // Lb = u2
  // u3 = u2 * u -> regs, overwrite La
  ld24(&Lb[p*24], a0); ld24(&Lb[(p+12)*24], a1);
  zero12(t0); zero12(t1);
  mmtile(a0, a1, La + c0, t0, t1);
  __syncthreads();                       // all reads of La(u) done
  st12(&La[p*24 + c0], t0); st12(&La[(p+12)*24 + c0], t1);
  __syncthreads();                       // La = u3; Lb free (u2-row reads done)

  float P0[12], P1[12];
#pragma unroll
  for (int j = 0; j < 12; ++j) {
    P0[j] = cf.c[10]*u0[j] + cf.c[11]*w0[j];
    P1[j] = cf.c[10]*u1[j] + cf.c[11]*w1[j];
  }
  add_diag(P0, P1, p, h, cf.c[9]);

#pragma unroll 1
  for (int jb = 2; jb >= 0; --jb) {
    st12(&Lb[p*24 + c0], P0); st12(&Lb[(p+12)*24 + c0], P1);
    __syncthreads();
    float acc0[12], acc1[12];
#pragma unroll
    for (int j = 0; j < 12; ++j) {
      acc0[j] = cf.c[3*jb+1]*u0[j] + cf.c[3*jb+2]*w0[j];
      acc1[j] = cf.c[3*jb+1]*u1[j] + cf.c[3*jb+2]*w1[j];
    }
    add_diag(acc0, acc1, p, h, cf.c[3*jb]);
    ld24(&Lb[p*24], a0); ld24(&Lb[(p+12)*24], a1);
    mmtile(a0, a1, La + c0, acc0, acc1);   // += P * u3
#pragma unroll
    for (int j = 0; j < 12; ++j) { P0[j] = acc0[j]; P1[j] = acc1[j]; }
    __syncthreads();                       // Lb(P-row) reads done before overwrite
  }
  st12(io + mat*576 + p*24 + c0, P0);
  st12(io + mat*576 + (p+12)*24 + c0, P1);
}

// ---------- K4: congruence + Frobenius norm + 9-step Newton-Schulz sqrt ----------
// Round-0 structure (LDS round-trip for A-rows: no shuffles, no spills), but
// with 2 LDS buffers instead of 3: Y and MT time-share Lb (Y is register-
// resident during the MT window). LDS 59904 -> 40704 B: 2 -> 4 blocks/CU.
// Same multiply order / operand values as the verified round-0 kernel.
__global__ __launch_bounds__(BLK) void k_csqrt(float* __restrict__ io,
                                               const float* __restrict__ W) {
  __shared__ __align__(16) float lds[MATS][2][LROW];   // 37632 B
  __shared__ __align__(16) float Wt[576];
  __shared__ float red[BLK];
  const int tid = threadIdx.x;
  const int lm = tid / 24, t24 = tid % 24, p = t24 >> 1, h = t24 & 1, c0 = h * 12;
  const long mat = (long)blockIdx.x * MATS + lm;
  float *La = lds[lm][0], *Lb = lds[lm][1];

  for (int i = tid; i < 576; i += BLK) {
    const int k = i / 24, j = i % 24;
    Wt[i] = W[j*24 + k];
  }
  {
    float e0[12], e1[12];
    ld12(io + mat*576 + p*24 + c0, e0);
    ld12(io + mat*576 + (p+12)*24 + c0, e1);
    st12(&La[p*24 + c0], e0); st12(&La[(p+12)*24 + c0], e1);
  }
  float a0[24], a1[24];
  ld24(W + p*24, a0); ld24(W + (p+12)*24, a1);    // W rows (A-operand)
  __syncthreads();                                // La = E, Wt ready

  float t0[12], t1[12];
  zero12(t0); zero12(t1);
  mmtile(a0, a1, La + c0, t0, t1);                // F = W * E
  st12(&Lb[p*24 + c0], t0); st12(&Lb[(p+12)*24 + c0], t1);
  __syncthreads();                                // Lb = F; La(E) reads done

  float ct0[12], ct1[12];
  zero12(ct0); zero12(ct1);
  ld24(&Lb[p*24], a0); ld24(&Lb[(p+12)*24], a1);
  mmtile(a0, a1, Wt + c0, ct0, ct1);              // C = F * W^T
  float s = 0.f;
#pragma unroll
  for (int j = 0; j < 12; ++j) s += ct0[j]*ct0[j] + ct1[j]*ct1[j];
  red[tid] = s;
  __syncthreads();                                // red ready; Lb(F-row) reads done
  float tot = 0.f;
#pragma unroll
  for (int q = 0; q < 24; ++q) tot += red[lm*24 + q];
  const float inv = 1.0f / sqrtf(tot);

  float Y0[12], Y1[12], M0[12], M1[12];
#pragma unroll
  for (int j = 0; j < 12; ++j) { M0[j] = ct0[j]*inv; M1[j] = ct1[j]*inv; }
  st12(&La[p*24 + c0], M0); st12(&La[(p+12)*24 + c0], M1);
  __syncthreads();                                // La = M0 (normalized)

  // ---- iter 0 (a=2, Y=M): Y1 = 2M - M*M ; M1 = (M*T)*T
  {
    float mm0[12], mm1[12];
    zero12(mm0); zero12(mm1);
    ld24(&La[p*24], a0); ld24(&La[(p+12)*24], a1);
    mmtile(a0, a1, La + c0, mm0, mm1);            // M*M
#pragma unroll
    for (int j = 0; j < 12; ++j) {
      Y0[j] = 2.f*M0[j] - mm0[j];                 // MT tiles (= new Y)
      Y1[j] = 2.f*M1[j] - mm1[j];
    }
    st12(&Lb[p*24 + c0], Y0); st12(&Lb[(p+12)*24 + c0], Y1);   // Lb free since F
    __syncthreads();                              // Lb = Y
    float q0[12], q1[12];
    zero12(q0); zero12(q1);
    ld24(&Lb[p*24], a0); ld24(&Lb[(p+12)*24], a1);
    mmtile(a0, a1, La + c0, q0, q1);              // (MT)*M
#pragma unroll
    for (int j = 0; j < 12; ++j) {
      M0[j] = 2.f*Y0[j] - q0[j];                  // newM = 2*MT - MT*M
      M1[j] = 2.f*Y1[j] - q1[j];
    }
    __syncthreads();                              // La(B) reads done
    st12(&La[p*24 + c0], M0); st12(&La[(p+12)*24 + c0], M1);
    __syncthreads();                              // La = M1; Lb keeps Y
  }

  // ---- iters 1..7
#pragma unroll 1
  for (int it = 1; it < 8; ++it) {
    const float aa = (it < 6) ? 2.0f : 1.5f;
    const float am1 = aa - 1.0f;
    float ym0[12], ym1[12];
    zero12(ym0); zero12(ym1);
    ld24(&Lb[p*24], a0); ld24(&Lb[(p+12)*24], a1);
    mmtile(a0, a1, La + c0, ym0, ym1);            // Y*M
    float mm0[12], mm1[12];
    zero12(mm0); zero12(mm1);
    ld24(&La[p*24], a0); ld24(&La[(p+12)*24], a1);
    mmtile(a0, a1, La + c0, mm0, mm1);            // M*M
#pragma unroll
    for (int j = 0; j < 12; ++j) {
      Y0[j] = aa*Y0[j] - am1*ym0[j];              // newY = Y*T
      Y1[j] = aa*Y1[j] - am1*ym1[j];
      mm0[j] = aa*M0[j] - am1*mm0[j];             // MT = M*T
      mm1[j] = aa*M1[j] - am1*mm1[j];
    }
    __syncthreads();                              // Lb(Y-row) + La reads done
    st12(&Lb[p*24 + c0], mm0); st12(&Lb[(p+12)*24 + c0], mm1); // Lb = MT
    __syncthreads();
    float q0[12], q1[12];
    zero12(q0); zero12(q1);
    ld24(&Lb[p*24], a0); ld24(&Lb[(p+12)*24], a1);
    mmtile(a0, a1, La + c0, q0, q1);              // (MT)*M
#pragma unroll
    for (int j = 0; j < 12; ++j) {
      M0[j] = aa*mm0[j] - am1*q0[j];              // newM = MT*T
      M1[j] = aa*mm1[j] - am1*q1[j];
    }
    __syncthreads();                              // Lb(MT-row) + La(B) reads done
    st12(&Lb[p*24 + c0], Y0); st12(&Lb[(p+12)*24 + c0], Y1);   // Lb = newY
    st12(&La[p*24 + c0], M0); st12(&La[(p+12)*24 + c0], M1);   // La = newM
    __syncthreads();
  }

  // ---- iter 8 (a=1.5): final Y = 1.5*Y - 0.5*(Y*M)
  {
    float ym0[12], ym1[12];
    zero12(ym0); zero12(ym1);
    ld24(&Lb[p*24], a0); ld24(&Lb[(p+12)*24], a1);
    mmtile(a0, a1, La + c0, ym0, ym1);
#pragma unroll
    for (int j = 0; j < 12; ++j) {
      Y0[j] = 1.5f*Y0[j] - 0.5f*ym0[j];
      Y1[j] = 1.5f*Y1[j] - 0.5f*ym1[j];
    }
  }
  st12(io + mat*576 + p*24 + c0, Y0);
  st12(io + mat*576 + (p+12)*24 + c0, Y1);
}

// ---------- host: Chebyshev interpolation -> monomial coefficients in u ----------
static void chebfit_host(double lo, double hi, int D, int islog, float* out) {
  const int N = 200;
  double a[32];
  for (int k = 0; k < 32; ++k) a[k] = 0.0;
  for (int i = 0; i < N; ++i) {
    double th = M_PI * (i + 0.5) / N;
    double u = cos(th);
    double xx = 0.5 * ((hi - lo) * u + (hi + lo));
    double f = islog ? log(xx) : exp(xx);
    for (int k = 0; k <= D; ++k) a[k] += f * cos(k * th);
  }
  for (int k = 0; k <= D; ++k) a[k] *= 2.0 / N;
  a[0] *= 0.5;
  double b[32], tp[32], tc[32], tn[32];
  for (int m = 0; m < 32; ++m) { b[m] = 0; tp[m] = 0; tc[m] = 0; tn[m] = 0; }
  tp[0] = 1.0; b[0] += a[0];
  tc[1] = 1.0; if (D >= 1) b[1] += a[1];
  for (int k = 2; k <= D; ++k) {
    for (int m = 0; m < 32; ++m) tn[m] = -tp[m];
    for (int m = 1; m < 32; ++m) tn[m] += 2.0 * tc[m-1];
    for (int m = 0; m <= k; ++m) b[m] += a[k] * tn[m];
    for (int m = 0; m < 32; ++m) { tp[m] = tc[m]; tc[m] = tn[m]; }
  }
  for (int m = 0; m < 32; ++m) out[m] = (float)b[m];
  out[30] = (float)(2.0 / (hi - lo));          // 1/d
  out[31] = (float)((hi + lo) / (hi - lo));    // c/d
}

extern "C" void kernel_launch(void* const* d_in, const int* in_sizes, int n_in,
                              void* d_out, int out_size, void* d_ws, size_t ws_size,
                              hipStream_t stream) {
  const float* x = (const float*)d_in[0];
  const float* A = (const float*)d_in[1];
  const float* W = (const float*)d_in[2];
  float* out = (float*)d_out;

  Coefs cl, ce;
  chebfit_host(0.47, 7.9, 23, 1, cl.c);   // log on the SPD input spectrum
  chebfit_host(-1.8, 3.9, 11, 0, ce.c);   // exp on the aggregated tangent spectrum

  k_logm <<<NMATS/MATS, BLK, 0, stream>>>(x, out, cl);
  k_agg  <<<NGROUPS,   256, 0, stream>>>(A, out);
  k_expm <<<NMATS/MATS, BLK, 0, stream>>>(out, ce);
  k_csqrt<<<NMATS/MATS, BLK, 0, stream>>>(out, W);
}

// Round 6
// 1164.860 us; speedup vs baseline: 4.4477x; 1.0371x over previous
//
#include <hip/hip_runtime.h>
#include <math.h>

#ifndef M_PI
#define M_PI 3.14159265358979323846
#endif

#define MATS 8
#define BLK 192           // MATS*24 threads; thread tile = 2 rows x 12 cols
#define NMATS 38400
#define NGROUPS 1536
#define LROW 588          // per-buffer stride in floats (24*24 + 12)

static_assert(BLK == MATS * 24, "block = MATS*24");

struct Coefs { float c[32]; };

// ---------- vector helpers (all fully unrolled; no dynamic reg indexing) ----------
__device__ __forceinline__ void ld12(const float* p, float* r) {
  const float4* q = (const float4*)p;
#pragma unroll
  for (int i = 0; i < 3; ++i) {
    float4 v = q[i];
    r[4*i+0] = v.x; r[4*i+1] = v.y; r[4*i+2] = v.z; r[4*i+3] = v.w;
  }
}
__device__ __forceinline__ void st12(float* p, const float* r) {
  float4* q = (float4*)p;
#pragma unroll
  for (int i = 0; i < 3; ++i)
    q[i] = make_float4(r[4*i+0], r[4*i+1], r[4*i+2], r[4*i+3]);
}
__device__ __forceinline__ void ld24(const float* p, float* r) {
  const float4* q = (const float4*)p;
#pragma unroll
  for (int i = 0; i < 6; ++i) {
    float4 v = q[i];
    r[4*i+0] = v.x; r[4*i+1] = v.y; r[4*i+2] = v.z; r[4*i+3] = v.w;
  }
}
__device__ __forceinline__ void zero12(float* r) {
#pragma unroll
  for (int j = 0; j < 12; ++j) r[j] = 0.f;
}
// += c on the diagonal elements that land in this thread's 2x12 tile
__device__ __forceinline__ void add_diag(float* t0, float* t1, int p, int h, float c) {
#pragma unroll
  for (int j = 0; j < 12; ++j) {
    t0[j] += (h == 0 && j == p) ? c : 0.f;
    t1[j] += (h == 1 && j == p) ? c : 0.f;
  }
}

// acc{0,1}[j] += sum_k a{0,1}[k] * B[k*24 + j]  (k_logm variant, A preloaded)
__device__ __forceinline__ void mmtile(const float* __restrict__ a0,
                                       const float* __restrict__ a1,
                                       const float* __restrict__ B,
                                       float* __restrict__ acc0,
                                       float* __restrict__ acc1) {
#pragma unroll
  for (int k = 0; k < 24; ++k) {
    float b[12];
    ld12(B + k*24, b);
    const float x0 = a0[k], x1 = a1[k];
#pragma unroll
    for (int j = 0; j < 12; ++j) { acc0[j] += x0 * b[j]; acc1[j] += x1 * b[j]; }
    if ((k % 6) == 5) __builtin_amdgcn_sched_barrier(0);
  }
}

// Register-lean variant: A rows are loaded in 12-float halves inside the loop
// (a-liveness 48 -> 24 regs). Accumulation order over k is identical to mmtile
// -> bitwise-identical results.
__device__ __forceinline__ void mmtileH(const float* __restrict__ rA0,
                                        const float* __restrict__ rA1,
                                        const float* __restrict__ B,
                                        float* __restrict__ acc0,
                                        float* __restrict__ acc1) {
#pragma unroll
  for (int half = 0; half < 2; ++half) {
    float a0[12], a1[12];
    ld12(rA0 + half*12, a0);
    ld12(rA1 + half*12, a1);
#pragma unroll
    for (int kk = 0; kk < 12; ++kk) {
      const int k = half*12 + kk;
      float b[12];
      ld12(B + k*24, b);
      const float x0 = a0[kk], x1 = a1[kk];
#pragma unroll
      for (int j = 0; j < 12; ++j) { acc0[j] += x0 * b[j]; acc1[j] += x1 * b[j]; }
      if ((kk % 6) == 5) __builtin_amdgcn_sched_barrier(0);
    }
  }
}

// ---------- K1: logm, degree-23 Chebyshev->monomial, PS k=4 (unchanged) ----------
__global__ __launch_bounds__(BLK) void k_logm(const float* __restrict__ x,
                                              float* __restrict__ out, Coefs cf) {
  __shared__ __align__(16) float lds[MATS][4][LROW];   // 75264 B -> 2 blocks/CU
  const int tid = threadIdx.x;
  const int lm = tid / 24, t24 = tid % 24, p = t24 >> 1, h = t24 & 1, c0 = h * 12;
  const long mat = (long)blockIdx.x * MATS + lm;
  float *L0 = lds[lm][0], *L1 = lds[lm][1], *L2 = lds[lm][2], *L3 = lds[lm][3];
  const float invd = cf.c[30], cd = cf.c[31];

  float u0[12], u1[12];
  ld12(x + mat*576 + p*24 + c0, u0);
  ld12(x + mat*576 + (p+12)*24 + c0, u1);
#pragma unroll
  for (int j = 0; j < 12; ++j) { u0[j] *= invd; u1[j] *= invd; }
  add_diag(u0, u1, p, h, -cd);
  st12(&L0[p*24 + c0], u0); st12(&L0[(p+12)*24 + c0], u1);
  __syncthreads();

  float a0[24], a1[24], t0[12], t1[12];
  // u2 -> L1
  ld24(&L0[p*24], a0); ld24(&L0[(p+12)*24], a1);
  zero12(t0); zero12(t1);
  mmtile(a0, a1, L0 + c0, t0, t1);
  st12(&L1[p*24 + c0], t0); st12(&L1[(p+12)*24 + c0], t1);
  __syncthreads();
  // u3 -> L2
  ld24(&L1[p*24], a0); ld24(&L1[(p+12)*24], a1);
  zero12(t0); zero12(t1);
  mmtile(a0, a1, L0 + c0, t0, t1);
  st12(&L2[p*24 + c0], t0); st12(&L2[(p+12)*24 + c0], t1);
  __syncthreads();
  // u4 -> (regs), then overwrite L0
  ld24(&L2[p*24], a0); ld24(&L2[(p+12)*24], a1);
  zero12(t0); zero12(t1);
  mmtile(a0, a1, L0 + c0, t0, t1);
  __syncthreads();                       // all reads of L0(=u) done
  st12(&L0[p*24 + c0], t0); st12(&L0[(p+12)*24 + c0], t1);
  __syncthreads();                       // L0 = u4 visible

  // top PS block jb=5: c20 I + c21 u + c22 u2 + c23 u3
  float P0[12], P1[12], w0[12], w1[12];
  ld12(&L1[p*24 + c0], w0); ld12(&L1[(p+12)*24 + c0], w1);
#pragma unroll
  for (int j = 0; j < 12; ++j) {
    P0[j] = cf.c[21]*u0[j] + cf.c[22]*w0[j];
    P1[j] = cf.c[21]*u1[j] + cf.c[22]*w1[j];
  }
  ld12(&L2[p*24 + c0], w0); ld12(&L2[(p+12)*24 + c0], w1);
#pragma unroll
  for (int j = 0; j < 12; ++j) { P0[j] += cf.c[23]*w0[j]; P1[j] += cf.c[23]*w1[j]; }
  add_diag(P0, P1, p, h, cf.c[20]);

#pragma unroll 1
  for (int jb = 4; jb >= 0; --jb) {
    st12(&L3[p*24 + c0], P0); st12(&L3[(p+12)*24 + c0], P1);
    __syncthreads();
    float acc0[12], acc1[12];
    ld12(&L1[p*24 + c0], w0); ld12(&L1[(p+12)*24 + c0], w1);
#pragma unroll
    for (int j = 0; j < 12; ++j) {
      acc0[j] = cf.c[4*jb+1]*u0[j] + cf.c[4*jb+2]*w0[j];
      acc1[j] = cf.c[4*jb+1]*u1[j] + cf.c[4*jb+2]*w1[j];
    }
    ld12(&L2[p*24 + c0], w0); ld12(&L2[(p+12)*24 + c0], w1);
#pragma unroll
    for (int j = 0; j < 12; ++j) { acc0[j] += cf.c[4*jb+3]*w0[j]; acc1[j] += cf.c[4*jb+3]*w1[j]; }
    add_diag(acc0, acc1, p, h, cf.c[4*jb]);
    ld24(&L3[p*24], a0); ld24(&L3[(p+12)*24], a1);
    mmtile(a0, a1, L0 + c0, acc0, acc1);   // += P * u4
#pragma unroll
    for (int j = 0; j < 12; ++j) { P0[j] = acc0[j]; P1[j] = acc1[j]; }
    __syncthreads();                       // L3 reads done before next overwrite
  }
  st12(out + mat*576 + p*24 + c0, P0);
  st12(out + mat*576 + (p+12)*24 + c0, P1);
}

// ---------- K2: graph aggregation (unchanged structure) ----------
__global__ __launch_bounds__(256) void k_agg(const float* __restrict__ A,
                                             float* __restrict__ io) {
  __shared__ __align__(16) float Lg[25*576];
  __shared__ float Ag[625];
  const int g = blockIdx.x;
  const float* Lbase = io + (long)g * 25 * 576;
  for (int i = threadIdx.x; i < 25*576/4; i += 256)
    ((float4*)Lg)[i] = ((const float4*)Lbase)[i];
  for (int i = threadIdx.x; i < 625; i += 256)
    Ag[i] = A[(long)g*625 + i];
  __syncthreads();
  for (int rr = threadIdx.x; rr < 600; rr += 256) {
    const int r = rr / 25, j = rr % 25;
    float acc[24];
#pragma unroll
    for (int q = 0; q < 24; ++q) acc[q] = 0.f;
#pragma unroll 1
    for (int v = 0; v < 25; ++v) {
      const float a = Ag[v*25 + j];
      float b[24];
      ld24(&Lg[v*576 + r*24], b);
#pragma unroll
      for (int q = 0; q < 24; ++q) acc[q] += a * b[q];
    }
    float* dst = io + ((long)g*25 + j)*576 + (long)r*24;
    float4* qd = (float4*)dst;
#pragma unroll
    for (int i = 0; i < 6; ++i)
      qd[i] = make_float4(acc[4*i], acc[4*i+1], acc[4*i+2], acc[4*i+3]);
  }
}

// ---------- K3: expm, degree-11 Chebyshev->monomial, PS k=3, in place ----------
// 2 LDS buffers; mmtileH + waves_per_eu=4 to get VGPR <= 128 (the occupancy
// step) -> 4 blocks/CU.
__global__ __launch_bounds__(BLK, 4) void k_expm(float* __restrict__ io, Coefs cf) {
  __shared__ __align__(16) float lds[MATS][2][LROW];   // 37632 B
  const int tid = threadIdx.x;
  const int lm = tid / 24, t24 = tid % 24, p = t24 >> 1, h = t24 & 1, c0 = h * 12;
  const long mat = (long)blockIdx.x * MATS + lm;
  float *La = lds[lm][0], *Lb = lds[lm][1];
  const float invd = cf.c[30], cd = cf.c[31];

  float u0[12], u1[12];
  ld12(io + mat*576 + p*24 + c0, u0);
  ld12(io + mat*576 + (p+12)*24 + c0, u1);
#pragma unroll
  for (int j = 0; j < 12; ++j) { u0[j] *= invd; u1[j] *= invd; }
  add_diag(u0, u1, p, h, -cd);
  st12(&La[p*24 + c0], u0); st12(&La[(p+12)*24 + c0], u1);
  __syncthreads();                       // La = u

  float t0[12], t1[12];
  // u2 tiles -> regs (w) and -> Lb (rows needed once for u3)
  zero12(t0); zero12(t1);
  mmtileH(&La[p*24], &La[(p+12)*24], La + c0, t0, t1);
  float w0[12], w1[12];
#pragma unroll
  for (int j = 0; j < 12; ++j) { w0[j] = t0[j]; w1[j] = t1[j]; }   // u2 tiles (persistent)
  st12(&Lb[p*24 + c0], t0); st12(&Lb[(p+12)*24 + c0], t1);
  __syncthreads();                       // Lb = u2
  // u3 = u2 * u -> regs, overwrite La
  zero12(t0); zero12(t1);
  mmtileH(&Lb[p*24], &Lb[(p+12)*24], La + c0, t0, t1);
  __syncthreads();                       // all reads of La(u) done
  st12(&La[p*24 + c0], t0); st12(&La[(p+12)*24 + c0], t1);
  __syncthreads();                       // La = u3; Lb free (u2-row reads done)

  float P0[12], P1[12];
#pragma unroll
  for (int j = 0; j < 12; ++j) {
    P0[j] = cf.c[10]*u0[j] + cf.c[11]*w0[j];
    P1[j] = cf.c[10]*u1[j] + cf.c[11]*w1[j];
  }
  add_diag(P0, P1, p, h, cf.c[9]);

#pragma unroll 1
  for (int jb = 2; jb >= 0; --jb) {
    st12(&Lb[p*24 + c0], P0); st12(&Lb[(p+12)*24 + c0], P1);
    __syncthreads();
    float acc0[12], acc1[12];
#pragma unroll
    for (int j = 0; j < 12; ++j) {
      acc0[j] = cf.c[3*jb+1]*u0[j] + cf.c[3*jb+2]*w0[j];
      acc1[j] = cf.c[3*jb+1]*u1[j] + cf.c[3*jb+2]*w1[j];
    }
    add_diag(acc0, acc1, p, h, cf.c[3*jb]);
    mmtileH(&Lb[p*24], &Lb[(p+12)*24], La + c0, acc0, acc1);   // += P * u3
#pragma unroll
    for (int j = 0; j < 12; ++j) { P0[j] = acc0[j]; P1[j] = acc1[j]; }
    __syncthreads();                       // Lb(P-row) reads done before overwrite
  }
  st12(io + mat*576 + p*24 + c0, P0);
  st12(io + mat*576 + (p+12)*24 + c0, P1);
}

// ---------- K4: congruence + Frobenius norm + 9-step Newton-Schulz sqrt ----------
// Same math/order as the verified round-0 kernel. Register diet: mmtileH
// (A rows loaded in halves), ym applied to Y before mm is computed (kills
// ym/mm overlap), waves_per_eu=4 -> VGPR <= 128 -> 4 blocks/CU with 40960 B LDS.
__global__ __launch_bounds__(BLK, 4) void k_csqrt(float* __restrict__ io,
                                                  const float* __restrict__ W) {
  __shared__ __align__(16) float lds[MATS][2][LROW];   // 37632 B
  __shared__ __align__(16) float Wt[576];
  __shared__ float red[BLK];
  const int tid = threadIdx.x;
  const int lm = tid / 24, t24 = tid % 24, p = t24 >> 1, h = t24 & 1, c0 = h * 12;
  const long mat = (long)blockIdx.x * MATS + lm;
  float *La = lds[lm][0], *Lb = lds[lm][1];

  for (int i = tid; i < 576; i += BLK) {
    const int k = i / 24, j = i % 24;
    Wt[i] = W[j*24 + k];
  }
  {
    float e0[12], e1[12];
    ld12(io + mat*576 + p*24 + c0, e0);
    ld12(io + mat*576 + (p+12)*24 + c0, e1);
    st12(&La[p*24 + c0], e0); st12(&La[(p+12)*24 + c0], e1);
  }
  __syncthreads();                                // La = E, Wt ready

  float t0[12], t1[12];
  zero12(t0); zero12(t1);
  mmtileH(W + p*24, W + (p+12)*24, La + c0, t0, t1);   // F = W * E (A rows from global)
  st12(&Lb[p*24 + c0], t0); st12(&Lb[(p+12)*24 + c0], t1);
  __syncthreads();                                // Lb = F; La(E) reads done

  float ct0[12], ct1[12];
  zero12(ct0); zero12(ct1);
  mmtileH(&Lb[p*24], &Lb[(p+12)*24], Wt + c0, ct0, ct1);   // C = F * W^T
  float s = 0.f;
#pragma unroll
  for (int j = 0; j < 12; ++j) s += ct0[j]*ct0[j] + ct1[j]*ct1[j];
  red[tid] = s;
  __syncthreads();                                // red ready; Lb(F-row) reads done
  float tot = 0.f;
#pragma unroll
  for (int q = 0; q < 24; ++q) tot += red[lm*24 + q];
  const float inv = 1.0f / sqrtf(tot);

  float Y0[12], Y1[12], M0[12], M1[12];
#pragma unroll
  for (int j = 0; j < 12; ++j) { M0[j] = ct0[j]*inv; M1[j] = ct1[j]*inv; }
  st12(&La[p*24 + c0], M0); st12(&La[(p+12)*24 + c0], M1);
  __syncthreads();                                // La = M0 (normalized)

  // ---- iter 0 (a=2, Y=M): Y1 = 2M - M*M ; M1 = (M*T)*T
  {
    float mm0[12], mm1[12];
    zero12(mm0); zero12(mm1);
    mmtileH(&La[p*24], &La[(p+12)*24], La + c0, mm0, mm1);   // M*M
#pragma unroll
    for (int j = 0; j < 12; ++j) {
      Y0[j] = 2.f*M0[j] - mm0[j];                 // MT tiles (= new Y)
      Y1[j] = 2.f*M1[j] - mm1[j];
    }
    st12(&Lb[p*24 + c0], Y0); st12(&Lb[(p+12)*24 + c0], Y1);   // Lb free since F
    __syncthreads();                              // Lb = Y
    float q0[12], q1[12];
    zero12(q0); zero12(q1);
    mmtileH(&Lb[p*24], &Lb[(p+12)*24], La + c0, q0, q1);      // (MT)*M
#pragma unroll
    for (int j = 0; j < 12; ++j) {
      M0[j] = 2.f*Y0[j] - q0[j];                  // newM = 2*MT - MT*M
      M1[j] = 2.f*Y1[j] - q1[j];
    }
    __syncthreads();                              // La(B) reads done
    st12(&La[p*24 + c0], M0); st12(&La[(p+12)*24 + c0], M1);
    __syncthreads();                              // La = M1; Lb keeps Y
  }

  // ---- iters 1..7 (ym applied before mm is computed: lower peak liveness,
  //      identical FP values — independent updates, same op order per value)
#pragma unroll 1
  for (int it = 1; it < 8; ++it) {
    const float aa = (it < 6) ? 2.0f : 1.5f;
    const float am1 = aa - 1.0f;
    float ym0[12], ym1[12];
    zero12(ym0); zero12(ym1);
    mmtileH(&Lb[p*24], &Lb[(p+12)*24], La + c0, ym0, ym1);   // Y*M
#pragma unroll
    for (int j = 0; j < 12; ++j) {
      Y0[j] = aa*Y0[j] - am1*ym0[j];              // newY = Y*T   (ym dies here)
      Y1[j] = aa*Y1[j] - am1*ym1[j];
    }
    float mm0[12], mm1[12];
    zero12(mm0); zero12(mm1);
    mmtileH(&La[p*24], &La[(p+12)*24], La + c0, mm0, mm1);   // M*M
#pragma unroll
    for (int j = 0; j < 12; ++j) {
      mm0[j] = aa*M0[j] - am1*mm0[j];             // MT = M*T    (M dies here)
      mm1[j] = aa*M1[j] - am1*mm1[j];
    }
    __syncthreads();                              // Lb(Y-row) + La reads done
    st12(&Lb[p*24 + c0], mm0); st12(&Lb[(p+12)*24 + c0], mm1); // Lb = MT
    __syncthreads();
    float q0[12], q1[12];
    zero12(q0); zero12(q1);
    mmtileH(&Lb[p*24], &Lb[(p+12)*24], La + c0, q0, q1);     // (MT)*M
#pragma unroll
    for (int j = 0; j < 12; ++j) {
      M0[j] = aa*mm0[j] - am1*q0[j];              // newM = MT*T
      M1[j] = aa*mm1[j] - am1*q1[j];
    }
    __syncthreads();                              // Lb(MT-row) + La(B) reads done
    st12(&Lb[p*24 + c0], Y0); st12(&Lb[(p+12)*24 + c0], Y1);   // Lb = newY
    st12(&La[p*24 + c0], M0); st12(&La[(p+12)*24 + c0], M1);   // La = newM
    __syncthreads();
  }

  // ---- iter 8 (a=1.5): final Y = 1.5*Y - 0.5*(Y*M)
  {
    float ym0[12], ym1[12];
    zero12(ym0); zero12(ym1);
    mmtileH(&Lb[p*24], &Lb[(p+12)*24], La + c0, ym0, ym1);
#pragma unroll
    for (int j = 0; j < 12; ++j) {
      Y0[j] = 1.5f*Y0[j] - 0.5f*ym0[j];
      Y1[j] = 1.5f*Y1[j] - 0.5f*ym1[j];
    }
  }
  st12(io + mat*576 + p*24 + c0, Y0);
  st12(io + mat*576 + (p+12)*24 + c0, Y1);
}

// ---------- host: Chebyshev interpolation -> monomial coefficients in u ----------
static void chebfit_host(double lo, double hi, int D, int islog, float* out) {
  const int N = 200;
  double a[32];
  for (int k = 0; k < 32; ++k) a[k] = 0.0;
  for (int i = 0; i < N; ++i) {
    double th = M_PI * (i + 0.5) / N;
    double u = cos(th);
    double xx = 0.5 * ((hi - lo) * u + (hi + lo));
    double f = islog ? log(xx) : exp(xx);
    for (int k = 0; k <= D; ++k) a[k] += f * cos(k * th);
  }
  for (int k = 0; k <= D; ++k) a[k] *= 2.0 / N;
  a[0] *= 0.5;
  double b[32], tp[32], tc[32], tn[32];
  for (int m = 0; m < 32; ++m) { b[m] = 0; tp[m] = 0; tc[m] = 0; tn[m] = 0; }
  tp[0] = 1.0; b[0] += a[0];
  tc[1] = 1.0; if (D >= 1) b[1] += a[1];
  for (int k = 2; k <= D; ++k) {
    for (int m = 0; m < 32; ++m) tn[m] = -tp[m];
    for (int m = 1; m < 32; ++m) tn[m] += 2.0 * tc[m-1];
    for (int m = 0; m <= k; ++m) b[m] += a[k] * tn[m];
    for (int m = 0; m < 32; ++m) { tp[m] = tc[m]; tc[m] = tn[m]; }
  }
  for (int m = 0; m < 32; ++m) out[m] = (float)b[m];
  out[30] = (float)(2.0 / (hi - lo));          // 1/d
  out[31] = (float)((hi + lo) / (hi - lo));    // c/d
}

extern "C" void kernel_launch(void* const* d_in, const int* in_sizes, int n_in,
                              void* d_out, int out_size, void* d_ws, size_t ws_size,
                              hipStream_t stream) {
  const float* x = (const float*)d_in[0];
  const float* A = (const float*)d_in[1];
  const float* W = (const float*)d_in[2];
  float* out = (float*)d_out;

  Coefs cl, ce;
  chebfit_host(0.47, 7.9, 23, 1, cl.c);   // log on the SPD input spectrum
  chebfit_host(-1.8, 3.9, 11, 0, ce.c);   // exp on the aggregated tangent spectrum

  k_logm <<<NMATS/MATS, BLK, 0, stream>>>(x, out, cl);
  k_agg  <<<NGROUPS,   256, 0, stream>>>(A, out);
  k_expm <<<NMATS/MATS, BLK, 0, stream>>>(out, ce);
  k_csqrt<<<NMATS/MATS, BLK, 0, stream>>>(out, W);
}

// Round 7
// 952.059 us; speedup vs baseline: 5.4419x; 1.2235x over previous
//
#include <hip/hip_runtime.h>
#include <math.h>

#ifndef M_PI
#define M_PI 3.14159265358979323846
#endif

#define MATS 8
#define BLK 192           // MATS*24 threads; thread tile = 2 rows x 12 cols
#define NMATS 38400
#define NGROUPS 1536
#define LROW 588          // per-buffer stride in floats (24*24 + 12)

static_assert(BLK == MATS * 24, "block = MATS*24");

struct Coefs { float c[32]; };

// ---------- vector helpers (all fully unrolled; no dynamic reg indexing) ----------
__device__ __forceinline__ void ld12(const float* p, float* r) {
  const float4* q = (const float4*)p;
#pragma unroll
  for (int i = 0; i < 3; ++i) {
    float4 v = q[i];
    r[4*i+0] = v.x; r[4*i+1] = v.y; r[4*i+2] = v.z; r[4*i+3] = v.w;
  }
}
__device__ __forceinline__ void st12(float* p, const float* r) {
  float4* q = (float4*)p;
#pragma unroll
  for (int i = 0; i < 3; ++i)
    q[i] = make_float4(r[4*i+0], r[4*i+1], r[4*i+2], r[4*i+3]);
}
__device__ __forceinline__ void ld24(const float* p, float* r) {
  const float4* q = (const float4*)p;
#pragma unroll
  for (int i = 0; i < 6; ++i) {
    float4 v = q[i];
    r[4*i+0] = v.x; r[4*i+1] = v.y; r[4*i+2] = v.z; r[4*i+3] = v.w;
  }
}
__device__ __forceinline__ void zero12(float* r) {
#pragma unroll
  for (int j = 0; j < 12; ++j) r[j] = 0.f;
}
// += c on the diagonal elements that land in this thread's 2x12 tile
__device__ __forceinline__ void add_diag(float* t0, float* t1, int p, int h, float c) {
#pragma unroll
  for (int j = 0; j < 12; ++j) {
    t0[j] += (h == 0 && j == p) ? c : 0.f;
    t1[j] += (h == 1 && j == p) ? c : 0.f;
  }
}

// acc{0,1}[j] += sum_k a{0,1}[k] * B[k*24 + j]  (k_logm variant, A preloaded)
__device__ __forceinline__ void mmtile(const float* __restrict__ a0,
                                       const float* __restrict__ a1,
                                       const float* __restrict__ B,
                                       float* __restrict__ acc0,
                                       float* __restrict__ acc1) {
#pragma unroll
  for (int k = 0; k < 24; ++k) {
    float b[12];
    ld12(B + k*24, b);
    const float x0 = a0[k], x1 = a1[k];
#pragma unroll
    for (int j = 0; j < 12; ++j) { acc0[j] += x0 * b[j]; acc1[j] += x1 * b[j]; }
    if ((k % 6) == 5) __builtin_amdgcn_sched_barrier(0);
  }
}

// Register-lean variant: A rows are loaded in 12-float halves inside the loop
// (a-liveness 48 -> 24 regs). Accumulation order over k identical to mmtile
// -> bitwise-identical results.
__device__ __forceinline__ void mmtileH(const float* __restrict__ rA0,
                                        const float* __restrict__ rA1,
                                        const float* __restrict__ B,
                                        float* __restrict__ acc0,
                                        float* __restrict__ acc1) {
#pragma unroll
  for (int half = 0; half < 2; ++half) {
    float a0[12], a1[12];
    ld12(rA0 + half*12, a0);
    ld12(rA1 + half*12, a1);
#pragma unroll
    for (int kk = 0; kk < 12; ++kk) {
      const int k = half*12 + kk;
      float b[12];
      ld12(B + k*24, b);
      const float x0 = a0[kk], x1 = a1[kk];
#pragma unroll
      for (int j = 0; j < 12; ++j) { acc0[j] += x0 * b[j]; acc1[j] += x1 * b[j]; }
      if ((kk % 6) == 5) __builtin_amdgcn_sched_barrier(0);
    }
  }
}

// ---------- K1: logm, degree-23 Chebyshev->monomial, PS k=4 (unchanged) ----------
__global__ __launch_bounds__(BLK) void k_logm(const float* __restrict__ x,
                                              float* __restrict__ out, Coefs cf) {
  __shared__ __align__(16) float lds[MATS][4][LROW];   // 75264 B -> 2 blocks/CU
  const int tid = threadIdx.x;
  const int lm = tid / 24, t24 = tid % 24, p = t24 >> 1, h = t24 & 1, c0 = h * 12;
  const long mat = (long)blockIdx.x * MATS + lm;
  float *L0 = lds[lm][0], *L1 = lds[lm][1], *L2 = lds[lm][2], *L3 = lds[lm][3];
  const float invd = cf.c[30], cd = cf.c[31];

  float u0[12], u1[12];
  ld12(x + mat*576 + p*24 + c0, u0);
  ld12(x + mat*576 + (p+12)*24 + c0, u1);
#pragma unroll
  for (int j = 0; j < 12; ++j) { u0[j] *= invd; u1[j] *= invd; }
  add_diag(u0, u1, p, h, -cd);
  st12(&L0[p*24 + c0], u0); st12(&L0[(p+12)*24 + c0], u1);
  __syncthreads();

  float a0[24], a1[24], t0[12], t1[12];
  // u2 -> L1
  ld24(&L0[p*24], a0); ld24(&L0[(p+12)*24], a1);
  zero12(t0); zero12(t1);
  mmtile(a0, a1, L0 + c0, t0, t1);
  st12(&L1[p*24 + c0], t0); st12(&L1[(p+12)*24 + c0], t1);
  __syncthreads();
  // u3 -> L2
  ld24(&L1[p*24], a0); ld24(&L1[(p+12)*24], a1);
  zero12(t0); zero12(t1);
  mmtile(a0, a1, L0 + c0, t0, t1);
  st12(&L2[p*24 + c0], t0); st12(&L2[(p+12)*24 + c0], t1);
  __syncthreads();
  // u4 -> (regs), then overwrite L0
  ld24(&L2[p*24], a0); ld24(&L2[(p+12)*24], a1);
  zero12(t0); zero12(t1);
  mmtile(a0, a1, L0 + c0, t0, t1);
  __syncthreads();                       // all reads of L0(=u) done
  st12(&L0[p*24 + c0], t0); st12(&L0[(p+12)*24 + c0], t1);
  __syncthreads();                       // L0 = u4 visible

  // top PS block jb=5: c20 I + c21 u + c22 u2 + c23 u3
  float P0[12], P1[12], w0[12], w1[12];
  ld12(&L1[p*24 + c0], w0); ld12(&L1[(p+12)*24 + c0], w1);
#pragma unroll
  for (int j = 0; j < 12; ++j) {
    P0[j] = cf.c[21]*u0[j] + cf.c[22]*w0[j];
    P1[j] = cf.c[21]*u1[j] + cf.c[22]*w1[j];
  }
  ld12(&L2[p*24 + c0], w0); ld12(&L2[(p+12)*24 + c0], w1);
#pragma unroll
  for (int j = 0; j < 12; ++j) { P0[j] += cf.c[23]*w0[j]; P1[j] += cf.c[23]*w1[j]; }
  add_diag(P0, P1, p, h, cf.c[20]);

#pragma unroll 1
  for (int jb = 4; jb >= 0; --jb) {
    st12(&L3[p*24 + c0], P0); st12(&L3[(p+12)*24 + c0], P1);
    __syncthreads();
    float acc0[12], acc1[12];
    ld12(&L1[p*24 + c0], w0); ld12(&L1[(p+12)*24 + c0], w1);
#pragma unroll
    for (int j = 0; j < 12; ++j) {
      acc0[j] = cf.c[4*jb+1]*u0[j] + cf.c[4*jb+2]*w0[j];
      acc1[j] = cf.c[4*jb+1]*u1[j] + cf.c[4*jb+2]*w1[j];
    }
    ld12(&L2[p*24 + c0], w0); ld12(&L2[(p+12)*24 + c0], w1);
#pragma unroll
    for (int j = 0; j < 12; ++j) { acc0[j] += cf.c[4*jb+3]*w0[j]; acc1[j] += cf.c[4*jb+3]*w1[j]; }
    add_diag(acc0, acc1, p, h, cf.c[4*jb]);
    ld24(&L3[p*24], a0); ld24(&L3[(p+12)*24], a1);
    mmtile(a0, a1, L0 + c0, acc0, acc1);   // += P * u4
#pragma unroll
    for (int j = 0; j < 12; ++j) { P0[j] = acc0[j]; P1[j] = acc1[j]; }
    __syncthreads();                       // L3 reads done before next overwrite
  }
  st12(out + mat*576 + p*24 + c0, P0);
  st12(out + mat*576 + (p+12)*24 + c0, P1);
}

// ---------- K2: graph aggregation (unchanged structure) ----------
__global__ __launch_bounds__(256) void k_agg(const float* __restrict__ A,
                                             float* __restrict__ io) {
  __shared__ __align__(16) float Lg[25*576];
  __shared__ float Ag[625];
  const int g = blockIdx.x;
  const float* Lbase = io + (long)g * 25 * 576;
  for (int i = threadIdx.x; i < 25*576/4; i += 256)
    ((float4*)Lg)[i] = ((const float4*)Lbase)[i];
  for (int i = threadIdx.x; i < 625; i += 256)
    Ag[i] = A[(long)g*625 + i];
  __syncthreads();
  for (int rr = threadIdx.x; rr < 600; rr += 256) {
    const int r = rr / 25, j = rr % 25;
    float acc[24];
#pragma unroll
    for (int q = 0; q < 24; ++q) acc[q] = 0.f;
#pragma unroll 1
    for (int v = 0; v < 25; ++v) {
      const float a = Ag[v*25 + j];
      float b[24];
      ld24(&Lg[v*576 + r*24], b);
#pragma unroll
      for (int q = 0; q < 24; ++q) acc[q] += a * b[q];
    }
    float* dst = io + ((long)g*25 + j)*576 + (long)r*24;
    float4* qd = (float4*)dst;
#pragma unroll
    for (int i = 0; i < 6; ++i)
      qd[i] = make_float4(acc[4*i], acc[4*i+1], acc[4*i+2], acc[4*i+3]);
  }
}

// ---------- K3: expm, degree-11 Chebyshev->monomial, PS k=3, in place ----------
// Register diet: P no longer register-persistent (stored to Lb at iteration
// end; rows re-read as A-operand). Persistent regs: u + w only.
__global__ __launch_bounds__(BLK, 4) void k_expm(float* __restrict__ io, Coefs cf) {
  __shared__ __align__(16) float lds[MATS][2][LROW];   // 37632 B
  const int tid = threadIdx.x;
  const int lm = tid / 24, t24 = tid % 24, p = t24 >> 1, h = t24 & 1, c0 = h * 12;
  const long mat = (long)blockIdx.x * MATS + lm;
  float *La = lds[lm][0], *Lb = lds[lm][1];
  const float invd = cf.c[30], cd = cf.c[31];

  float u0[12], u1[12];
  ld12(io + mat*576 + p*24 + c0, u0);
  ld12(io + mat*576 + (p+12)*24 + c0, u1);
#pragma unroll
  for (int j = 0; j < 12; ++j) { u0[j] *= invd; u1[j] *= invd; }
  add_diag(u0, u1, p, h, -cd);
  st12(&La[p*24 + c0], u0); st12(&La[(p+12)*24 + c0], u1);
  __syncthreads();                       // La = u

  float t0[12], t1[12];
  // u2 tiles -> regs (w) and -> Lb (rows needed once for u3)
  zero12(t0); zero12(t1);
  mmtileH(&La[p*24], &La[(p+12)*24], La + c0, t0, t1);
  float w0[12], w1[12];
#pragma unroll
  for (int j = 0; j < 12; ++j) { w0[j] = t0[j]; w1[j] = t1[j]; }   // u2 tiles (persistent)
  st12(&Lb[p*24 + c0], t0); st12(&Lb[(p+12)*24 + c0], t1);
  __syncthreads();                       // Lb = u2
  // u3 = u2 * u -> regs, overwrite La
  zero12(t0); zero12(t1);
  mmtileH(&Lb[p*24], &Lb[(p+12)*24], La + c0, t0, t1);
  __syncthreads();                       // all reads of La(u) + Lb(u2) done
  st12(&La[p*24 + c0], t0); st12(&La[(p+12)*24 + c0], t1);
  __syncthreads();                       // La = u3; Lb free

  // initial P (jb=3 top block): c9 I + c10 u + c11 u2 -> Lb
#pragma unroll
  for (int j = 0; j < 12; ++j) {
    t0[j] = cf.c[10]*u0[j] + cf.c[11]*w0[j];
    t1[j] = cf.c[10]*u1[j] + cf.c[11]*w1[j];
  }
  add_diag(t0, t1, p, h, cf.c[9]);
  st12(&Lb[p*24 + c0], t0); st12(&Lb[(p+12)*24 + c0], t1);
  __syncthreads();                       // Lb = P

#pragma unroll 1
  for (int jb = 2; jb >= 0; --jb) {
    float acc0[12], acc1[12];
#pragma unroll
    for (int j = 0; j < 12; ++j) {
      acc0[j] = cf.c[3*jb+1]*u0[j] + cf.c[3*jb+2]*w0[j];
      acc1[j] = cf.c[3*jb+1]*u1[j] + cf.c[3*jb+2]*w1[j];
    }
    add_diag(acc0, acc1, p, h, cf.c[3*jb]);
    mmtileH(&Lb[p*24], &Lb[(p+12)*24], La + c0, acc0, acc1);   // += P * u3
    if (jb > 0) {
      __syncthreads();                   // Lb(P-row) reads done
      st12(&Lb[p*24 + c0], acc0); st12(&Lb[(p+12)*24 + c0], acc1);
      __syncthreads();                   // Lb = newP
    } else {
      st12(io + mat*576 + p*24 + c0, acc0);
      st12(io + mat*576 + (p+12)*24 + c0, acc1);
    }
  }
}

// ---------- K4: congruence + Frobenius norm + 9-step Newton-Schulz sqrt ----------
// Register diet round 2: Y/M tiles are NOT register-persistent — they live in
// Lb/La and the 2x12 tile is re-read via ld12 at each update point (identical
// bits to the old register copy -> FP-identical). Iteration order: MT-phase,
// newY-phase, store MT, q-phase, store newY/newM. Peak live ~2 tiles + acc.
// Target VGPR <= 128 (occupancy step) -> 4 blocks/CU at 40960 B LDS.
__global__ __launch_bounds__(BLK, 4) void k_csqrt(float* __restrict__ io,
                                                  const float* __restrict__ W) {
  __shared__ __align__(16) float lds[MATS][2][LROW];   // 37632 B
  __shared__ __align__(16) float Wt[576];
  __shared__ float red[BLK];
  const int tid = threadIdx.x;
  const int lm = tid / 24, t24 = tid % 24, p = t24 >> 1, h = t24 & 1, c0 = h * 12;
  const long mat = (long)blockIdx.x * MATS + lm;
  float *La = lds[lm][0], *Lb = lds[lm][1];

  for (int i = tid; i < 576; i += BLK) {
    const int k = i / 24, j = i % 24;
    Wt[i] = W[j*24 + k];
  }
  {
    float e0[12], e1[12];
    ld12(io + mat*576 + p*24 + c0, e0);
    ld12(io + mat*576 + (p+12)*24 + c0, e1);
    st12(&La[p*24 + c0], e0); st12(&La[(p+12)*24 + c0], e1);
  }
  __syncthreads();                                // La = E, Wt ready

  {
    float t0[12], t1[12];
    zero12(t0); zero12(t1);
    mmtileH(W + p*24, W + (p+12)*24, La + c0, t0, t1);   // F = W * E
    st12(&Lb[p*24 + c0], t0); st12(&Lb[(p+12)*24 + c0], t1);
  }
  __syncthreads();                                // Lb = F; La(E) reads done

  {
    float ct0[12], ct1[12];
    zero12(ct0); zero12(ct1);
    mmtileH(&Lb[p*24], &Lb[(p+12)*24], Wt + c0, ct0, ct1);   // C = F * W^T
    float s = 0.f;
#pragma unroll
    for (int j = 0; j < 12; ++j) s += ct0[j]*ct0[j] + ct1[j]*ct1[j];
    red[tid] = s;
    __syncthreads();                              // red ready; Lb(F-row) reads done
    float tot = 0.f;
#pragma unroll
    for (int q = 0; q < 24; ++q) tot += red[lm*24 + q];
    const float inv = 1.0f / sqrtf(tot);
#pragma unroll
    for (int j = 0; j < 12; ++j) { ct0[j] *= inv; ct1[j] *= inv; }
    st12(&La[p*24 + c0], ct0); st12(&La[(p+12)*24 + c0], ct1);
  }
  __syncthreads();                                // La = M0 (normalized)

  // ---- iter 0 (a=2, Y=M): newY(=MT) = 2M - M*M ; newM = 2*MT - MT*M
  {
    float mm0[12], mm1[12];
    zero12(mm0); zero12(mm1);
    mmtileH(&La[p*24], &La[(p+12)*24], La + c0, mm0, mm1);   // M*M
    {
      float mt0[12], mt1[12];
      ld12(&La[p*24 + c0], mt0); ld12(&La[(p+12)*24 + c0], mt1);
#pragma unroll
      for (int j = 0; j < 12; ++j) {
        mm0[j] = 2.f*mt0[j] - mm0[j];             // MT tile = newY
        mm1[j] = 2.f*mt1[j] - mm1[j];
      }
    }
    st12(&Lb[p*24 + c0], mm0); st12(&Lb[(p+12)*24 + c0], mm1);  // Lb free since F
    __syncthreads();                              // Lb = MT(=Y) visible
    float q0[12], q1[12];
    zero12(q0); zero12(q1);
    mmtileH(&Lb[p*24], &Lb[(p+12)*24], La + c0, q0, q1);        // MT*M
    {
      float mt0[12], mt1[12];
      ld12(&Lb[p*24 + c0], mt0); ld12(&Lb[(p+12)*24 + c0], mt1);
#pragma unroll
      for (int j = 0; j < 12; ++j) {
        q0[j] = 2.f*mt0[j] - q0[j];               // newM
        q1[j] = 2.f*mt1[j] - q1[j];
      }
    }
    __syncthreads();                              // La(M)/Lb(MT) reads done
    st12(&La[p*24 + c0], q0); st12(&La[(p+12)*24 + c0], q1);
    __syncthreads();                              // La = newM; Lb = Y
  }

  // ---- iters 1..7: phases {MT, newY, store MT, q, store newY/newM}
#pragma unroll 1
  for (int it = 1; it < 8; ++it) {
    const float aa = (it < 6) ? 2.0f : 1.5f;
    const float am1 = aa - 1.0f;
    // MT tile: aa*M - am1*(M*M)
    float mm0[12], mm1[12];
    zero12(mm0); zero12(mm1);
    mmtileH(&La[p*24], &La[(p+12)*24], La + c0, mm0, mm1);   // M*M
    {
      float mt0[12], mt1[12];
      ld12(&La[p*24 + c0], mt0); ld12(&La[(p+12)*24 + c0], mt1);
#pragma unroll
      for (int j = 0; j < 12; ++j) {
        mm0[j] = aa*mt0[j] - am1*mm0[j];
        mm1[j] = aa*mt1[j] - am1*mm1[j];
      }
    }
    // newY tile: aa*Y - am1*(Y*M)
    float yn0[12], yn1[12];
    zero12(yn0); zero12(yn1);
    mmtileH(&Lb[p*24], &Lb[(p+12)*24], La + c0, yn0, yn1);   // Y*M
    {
      float yt0[12], yt1[12];
      ld12(&Lb[p*24 + c0], yt0); ld12(&Lb[(p+12)*24 + c0], yt1);
#pragma unroll
      for (int j = 0; j < 12; ++j) {
        yn0[j] = aa*yt0[j] - am1*yn0[j];
        yn1[j] = aa*yt1[j] - am1*yn1[j];
      }
    }
    __syncthreads();                              // Lb(Y)/La(M) reads done
    st12(&Lb[p*24 + c0], mm0); st12(&Lb[(p+12)*24 + c0], mm1); // Lb = MT
    __syncthreads();
    // newM: aa*MT - am1*(MT*M)
    float q0[12], q1[12];
    zero12(q0); zero12(q1);
    mmtileH(&Lb[p*24], &Lb[(p+12)*24], La + c0, q0, q1);     // MT*M
    {
      float mt0[12], mt1[12];
      ld12(&Lb[p*24 + c0], mt0); ld12(&Lb[(p+12)*24 + c0], mt1);
#pragma unroll
      for (int j = 0; j < 12; ++j) {
        q0[j] = aa*mt0[j] - am1*q0[j];
        q1[j] = aa*mt1[j] - am1*q1[j];
      }
    }
    __syncthreads();                              // Lb(MT)/La(M) reads done
    st12(&Lb[p*24 + c0], yn0); st12(&Lb[(p+12)*24 + c0], yn1); // Lb = newY
    st12(&La[p*24 + c0], q0); st12(&La[(p+12)*24 + c0], q1);   // La = newM
    __syncthreads();
  }

  // ---- iter 8 (a=1.5): final Y = 1.5*Y - 0.5*(Y*M)
  {
    float ym0[12], ym1[12];
    zero12(ym0); zero12(ym1);
    mmtileH(&Lb[p*24], &Lb[(p+12)*24], La + c0, ym0, ym1);
    float yt0[12], yt1[12];
    ld12(&Lb[p*24 + c0], yt0); ld12(&Lb[(p+12)*24 + c0], yt1);
#pragma unroll
    for (int j = 0; j < 12; ++j) {
      ym0[j] = 1.5f*yt0[j] - 0.5f*ym0[j];
      ym1[j] = 1.5f*yt1[j] - 0.5f*ym1[j];
    }
    st12(io + mat*576 + p*24 + c0, ym0);
    st12(io + mat*576 + (p+12)*24 + c0, ym1);
  }
}

// ---------- host: Chebyshev interpolation -> monomial coefficients in u ----------
static void chebfit_host(double lo, double hi, int D, int islog, float* out) {
  const int N = 200;
  double a[32];
  for (int k = 0; k < 32; ++k) a[k] = 0.0;
  for (int i = 0; i < N; ++i) {
    double th = M_PI * (i + 0.5) / N;
    double u = cos(th);
    double xx = 0.5 * ((hi - lo) * u + (hi + lo));
    double f = islog ? log(xx) : exp(xx);
    for (int k = 0; k <= D; ++k) a[k] += f * cos(k * th);
  }
  for (int k = 0; k <= D; ++k) a[k] *= 2.0 / N;
  a[0] *= 0.5;
  double b[32], tp[32], tc[32], tn[32];
  for (int m = 0; m < 32; ++m) { b[m] = 0; tp[m] = 0; tc[m] = 0; tn[m] = 0; }
  tp[0] = 1.0; b[0] += a[0];
  tc[1] = 1.0; if (D >= 1) b[1] += a[1];
  for (int k = 2; k <= D; ++k) {
    for (int m = 0; m < 32; ++m) tn[m] = -tp[m];
    for (int m = 1; m < 32; ++m) tn[m] += 2.0 * tc[m-1];
    for (int m = 0; m <= k; ++m) b[m] += a[k] * tn[m];
    for (int m = 0; m < 32; ++m) { tp[m] = tc[m]; tc[m] = tn[m]; }
  }
  for (int m = 0; m < 32; ++m) out[m] = (float)b[m];
  out[30] = (float)(2.0 / (hi - lo));          // 1/d
  out[31] = (float)((hi + lo) / (hi - lo));    // c/d
}

extern "C" void kernel_launch(void* const* d_in, const int* in_sizes, int n_in,
                              void* d_out, int out_size, void* d_ws, size_t ws_size,
                              hipStream_t stream) {
  const float* x = (const float*)d_in[0];
  const float* A = (const float*)d_in[1];
  const float* W = (const float*)d_in[2];
  float* out = (float*)d_out;

  Coefs cl, ce;
  chebfit_host(0.47, 7.9, 23, 1, cl.c);   // log on the SPD input spectrum
  chebfit_host(-1.8, 3.9, 11, 0, ce.c);   // exp on the aggregated tangent spectrum

  k_logm <<<NMATS/MATS, BLK, 0, stream>>>(x, out, cl);
  k_agg  <<<NGROUPS,   256, 0, stream>>>(A, out);
  k_expm <<<NMATS/MATS, BLK, 0, stream>>>(out, ce);
  k_csqrt<<<NMATS/MATS, BLK, 0, stream>>>(out, W);
}

// Round 10
// 943.800 us; speedup vs baseline: 5.4895x; 1.0088x over previous
//
#include <hip/hip_runtime.h>
#include <math.h>

#ifndef M_PI
#define M_PI 3.14159265358979323846
#endif

#define MATS 8
#define BLK 192           // k_logm/k_expm: MATS*24 threads; tile = 2r x 12c
#define MATS4 16          // k_csqrt: 12 threads/matrix, tile = 4r x 12c
#define NMATS 38400
#define NGROUPS 1536
#define LROW 588          // per-buffer stride in floats (24*24 + 12)

static_assert(BLK == MATS * 24, "block = MATS*24");
static_assert(BLK == MATS4 * 12, "block = MATS4*12");

struct Coefs { float c[32]; };

// ---------- vector helpers (all fully unrolled; no dynamic reg indexing) ----------
__device__ __forceinline__ void ld12(const float* p, float* r) {
  const float4* q = (const float4*)p;
#pragma unroll
  for (int i = 0; i < 3; ++i) {
    float4 v = q[i];
    r[4*i+0] = v.x; r[4*i+1] = v.y; r[4*i+2] = v.z; r[4*i+3] = v.w;
  }
}
__device__ __forceinline__ void st12(float* p, const float* r) {
  float4* q = (float4*)p;
#pragma unroll
  for (int i = 0; i < 3; ++i)
    q[i] = make_float4(r[4*i+0], r[4*i+1], r[4*i+2], r[4*i+3]);
}
__device__ __forceinline__ void ld24(const float* p, float* r) {
  const float4* q = (const float4*)p;
#pragma unroll
  for (int i = 0; i < 6; ++i) {
    float4 v = q[i];
    r[4*i+0] = v.x; r[4*i+1] = v.y; r[4*i+2] = v.z; r[4*i+3] = v.w;
  }
}
__device__ __forceinline__ void zero12(float* r) {
#pragma unroll
  for (int j = 0; j < 12; ++j) r[j] = 0.f;
}
// += c on the diagonal elements that land in this thread's 2x12 tile
__device__ __forceinline__ void add_diag(float* t0, float* t1, int p, int h, float c) {
#pragma unroll
  for (int j = 0; j < 12; ++j) {
    t0[j] += (h == 0 && j == p) ? c : 0.f;
    t1[j] += (h == 1 && j == p) ? c : 0.f;
  }
}

// acc{0,1}[j] += sum_k a{0,1}[k] * B[k*24 + j]  (k_logm variant, A preloaded)
__device__ __forceinline__ void mmtile(const float* __restrict__ a0,
                                       const float* __restrict__ a1,
                                       const float* __restrict__ B,
                                       float* __restrict__ acc0,
                                       float* __restrict__ acc1) {
#pragma unroll
  for (int k = 0; k < 24; ++k) {
    float b[12];
    ld12(B + k*24, b);
    const float x0 = a0[k], x1 = a1[k];
#pragma unroll
    for (int j = 0; j < 12; ++j) { acc0[j] += x0 * b[j]; acc1[j] += x1 * b[j]; }
    if ((k % 6) == 5) __builtin_amdgcn_sched_barrier(0);
  }
}

// Register-lean 2-row variant (k_expm): A rows loaded in 12-float halves.
__device__ __forceinline__ void mmtileH(const float* __restrict__ rA0,
                                        const float* __restrict__ rA1,
                                        const float* __restrict__ B,
                                        float* __restrict__ acc0,
                                        float* __restrict__ acc1) {
#pragma unroll
  for (int half = 0; half < 2; ++half) {
    float a0[12], a1[12];
    ld12(rA0 + half*12, a0);
    ld12(rA1 + half*12, a1);
#pragma unroll
    for (int kk = 0; kk < 12; ++kk) {
      const int k = half*12 + kk;
      float b[12];
      ld12(B + k*24, b);
      const float x0 = a0[kk], x1 = a1[kk];
#pragma unroll
      for (int j = 0; j < 12; ++j) { acc0[j] += x0 * b[j]; acc1[j] += x1 * b[j]; }
      if ((kk % 6) == 5) __builtin_amdgcn_sched_barrier(0);
    }
  }
}

// 4-row variant (k_csqrt): one B read serves 4 output rows -> LDS instr per
// matrix-matmul drops 31.5 -> 18 (the LDS-issue bottleneck). k-order per
// output element identical to mmtileH -> bitwise-identical products.
__device__ __forceinline__ void mmtile4(const float* __restrict__ rA0,
                                        const float* __restrict__ rA1,
                                        const float* __restrict__ rA2,
                                        const float* __restrict__ rA3,
                                        const float* __restrict__ B,
                                        float* __restrict__ acc0,
                                        float* __restrict__ acc1,
                                        float* __restrict__ acc2,
                                        float* __restrict__ acc3) {
#pragma unroll
  for (int half = 0; half < 2; ++half) {
    float a0[12], a1[12], a2[12], a3[12];
    ld12(rA0 + half*12, a0); ld12(rA1 + half*12, a1);
    ld12(rA2 + half*12, a2); ld12(rA3 + half*12, a3);
#pragma unroll
    for (int kk = 0; kk < 12; ++kk) {
      const int k = half*12 + kk;
      float b[12];
      ld12(B + k*24, b);
      const float x0 = a0[kk], x1 = a1[kk], x2 = a2[kk], x3 = a3[kk];
#pragma unroll
      for (int j = 0; j < 12; ++j) {
        acc0[j] += x0 * b[j]; acc1[j] += x1 * b[j];
        acc2[j] += x2 * b[j]; acc3[j] += x3 * b[j];
      }
      if ((kk % 6) == 5) __builtin_amdgcn_sched_barrier(0);
    }
  }
}

// ---------- K1: logm, degree-23 Chebyshev->monomial, PS k=4 (unchanged) ----------
__global__ __launch_bounds__(BLK) void k_logm(const float* __restrict__ x,
                                              float* __restrict__ out, Coefs cf) {
  __shared__ __align__(16) float lds[MATS][4][LROW];   // 75264 B -> 2 blocks/CU
  const int tid = threadIdx.x;
  const int lm = tid / 24, t24 = tid % 24, p = t24 >> 1, h = t24 & 1, c0 = h * 12;
  const long mat = (long)blockIdx.x * MATS + lm;
  float *L0 = lds[lm][0], *L1 = lds[lm][1], *L2 = lds[lm][2], *L3 = lds[lm][3];
  const float invd = cf.c[30], cd = cf.c[31];

  float u0[12], u1[12];
  ld12(x + mat*576 + p*24 + c0, u0);
  ld12(x + mat*576 + (p+12)*24 + c0, u1);
#pragma unroll
  for (int j = 0; j < 12; ++j) { u0[j] *= invd; u1[j] *= invd; }
  add_diag(u0, u1, p, h, -cd);
  st12(&L0[p*24 + c0], u0); st12(&L0[(p+12)*24 + c0], u1);
  __syncthreads();

  float a0[24], a1[24], t0[12], t1[12];
  // u2 -> L1
  ld24(&L0[p*24], a0); ld24(&L0[(p+12)*24], a1);
  zero12(t0); zero12(t1);
  mmtile(a0, a1, L0 + c0, t0, t1);
  st12(&L1[p*24 + c0], t0); st12(&L1[(p+12)*24 + c0], t1);
  __syncthreads();
  // u3 -> L2
  ld24(&L1[p*24], a0); ld24(&L1[(p+12)*24], a1);
  zero12(t0); zero12(t1);
  mmtile(a0, a1, L0 + c0, t0, t1);
  st12(&L2[p*24 + c0], t0); st12(&L2[(p+12)*24 + c0], t1);
  __syncthreads();
  // u4 -> (regs), then overwrite L0
  ld24(&L2[p*24], a0); ld24(&L2[(p+12)*24], a1);
  zero12(t0); zero12(t1);
  mmtile(a0, a1, L0 + c0, t0, t1);
  __syncthreads();                       // all reads of L0(=u) done
  st12(&L0[p*24 + c0], t0); st12(&L0[(p+12)*24 + c0], t1);
  __syncthreads();                       // L0 = u4 visible

  // top PS block jb=5: c20 I + c21 u + c22 u2 + c23 u3
  float P0[12], P1[12], w0[12], w1[12];
  ld12(&L1[p*24 + c0], w0); ld12(&L1[(p+12)*24 + c0], w1);
#pragma unroll
  for (int j = 0; j < 12; ++j) {
    P0[j] = cf.c[21]*u0[j] + cf.c[22]*w0[j];
    P1[j] = cf.c[21]*u1[j] + cf.c[22]*w1[j];
  }
  ld12(&L2[p*24 + c0], w0); ld12(&L2[(p+12)*24 + c0], w1);
#pragma unroll
  for (int j = 0; j < 12; ++j) { P0[j] += cf.c[23]*w0[j]; P1[j] += cf.c[23]*w1[j]; }
  add_diag(P0, P1, p, h, cf.c[20]);

#pragma unroll 1
  for (int jb = 4; jb >= 0; --jb) {
    st12(&L3[p*24 + c0], P0); st12(&L3[(p+12)*24 + c0], P1);
    __syncthreads();
    float acc0[12], acc1[12];
    ld12(&L1[p*24 + c0], w0); ld12(&L1[(p+12)*24 + c0], w1);
#pragma unroll
    for (int j = 0; j < 12; ++j) {
      acc0[j] = cf.c[4*jb+1]*u0[j] + cf.c[4*jb+2]*w0[j];
      acc1[j] = cf.c[4*jb+1]*u1[j] + cf.c[4*jb+2]*w1[j];
    }
    ld12(&L2[p*24 + c0], w0); ld12(&L2[(p+12)*24 + c0], w1);
#pragma unroll
    for (int j = 0; j < 12; ++j) { acc0[j] += cf.c[4*jb+3]*w0[j]; acc1[j] += cf.c[4*jb+3]*w1[j]; }
    add_diag(acc0, acc1, p, h, cf.c[4*jb]);
    ld24(&L3[p*24], a0); ld24(&L3[(p+12)*24], a1);
    mmtile(a0, a1, L0 + c0, acc0, acc1);   // += P * u4
#pragma unroll
    for (int j = 0; j < 12; ++j) { P0[j] = acc0[j]; P1[j] = acc1[j]; }
    __syncthreads();                       // L3 reads done before next overwrite
  }
  st12(out + mat*576 + p*24 + c0, P0);
  st12(out + mat*576 + (p+12)*24 + c0, P1);
}

// ---------- K2: graph aggregation (unchanged structure) ----------
__global__ __launch_bounds__(256) void k_agg(const float* __restrict__ A,
                                             float* __restrict__ io) {
  __shared__ __align__(16) float Lg[25*576];
  __shared__ float Ag[625];
  const int g = blockIdx.x;
  const float* Lbase = io + (long)g * 25 * 576;
  for (int i = threadIdx.x; i < 25*576/4; i += 256)
    ((float4*)Lg)[i] = ((const float4*)Lbase)[i];
  for (int i = threadIdx.x; i < 625; i += 256)
    Ag[i] = A[(long)g*625 + i];
  __syncthreads();
  for (int rr = threadIdx.x; rr < 600; rr += 256) {
    const int r = rr / 25, j = rr % 25;
    float acc[24];
#pragma unroll
    for (int q = 0; q < 24; ++q) acc[q] = 0.f;
#pragma unroll 1
    for (int v = 0; v < 25; ++v) {
      const float a = Ag[v*25 + j];
      float b[24];
      ld24(&Lg[v*576 + r*24], b);
#pragma unroll
      for (int q = 0; q < 24; ++q) acc[q] += a * b[q];
    }
    float* dst = io + ((long)g*25 + j)*576 + (long)r*24;
    float4* qd = (float4*)dst;
#pragma unroll
    for (int i = 0; i < 6; ++i)
      qd[i] = make_float4(acc[4*i], acc[4*i+1], acc[4*i+2], acc[4*i+3]);
  }
}

// ---------- K3: expm, degree-11 Chebyshev->monomial, PS k=3 (round-7, verified) ----------
__global__ __launch_bounds__(BLK, 4) void k_expm(float* __restrict__ io, Coefs cf) {
  __shared__ __align__(16) float lds[MATS][2][LROW];   // 37632 B
  const int tid = threadIdx.x;
  const int lm = tid / 24, t24 = tid % 24, p = t24 >> 1, h = t24 & 1, c0 = h * 12;
  const long mat = (long)blockIdx.x * MATS + lm;
  float *La = lds[lm][0], *Lb = lds[lm][1];
  const float invd = cf.c[30], cd = cf.c[31];

  float u0[12], u1[12];
  ld12(io + mat*576 + p*24 + c0, u0);
  ld12(io + mat*576 + (p+12)*24 + c0, u1);
#pragma unroll
  for (int j = 0; j < 12; ++j) { u0[j] *= invd; u1[j] *= invd; }
  add_diag(u0, u1, p, h, -cd);
  st12(&La[p*24 + c0], u0); st12(&La[(p+12)*24 + c0], u1);
  __syncthreads();                       // La = u

  float t0[12], t1[12];
  // u2 tiles -> regs (w) and -> Lb (rows needed once for u3)
  zero12(t0); zero12(t1);
  mmtileH(&La[p*24], &La[(p+12)*24], La + c0, t0, t1);
  float w0[12], w1[12];
#pragma unroll
  for (int j = 0; j < 12; ++j) { w0[j] = t0[j]; w1[j] = t1[j]; }   // u2 tiles (persistent)
  st12(&Lb[p*24 + c0], t0); st12(&Lb[(p+12)*24 + c0], t1);
  __syncthreads();                       // Lb = u2
  // u3 = u2 * u -> regs, overwrite La
  zero12(t0); zero12(t1);
  mmtileH(&Lb[p*24], &Lb[(p+12)*24], La + c0, t0, t1);
  __syncthreads();                       // all reads of La(u) + Lb(u2) done
  st12(&La[p*24 + c0], t0); st12(&La[(p+12)*24 + c0], t1);
  __syncthreads();                       // La = u3; Lb free

  // initial P (jb=3 top block): c9 I + c10 u + c11 u2 -> Lb
#pragma unroll
  for (int j = 0; j < 12; ++j) {
    t0[j] = cf.c[10]*u0[j] + cf.c[11]*w0[j];
    t1[j] = cf.c[10]*u1[j] + cf.c[11]*w1[j];
  }
  add_diag(t0, t1, p, h, cf.c[9]);
  st12(&Lb[p*24 + c0], t0); st12(&Lb[(p+12)*24 + c0], t1);
  __syncthreads();                       // Lb = P

#pragma unroll 1
  for (int jb = 2; jb >= 0; --jb) {
    float acc0[12], acc1[12];
#pragma unroll
    for (int j = 0; j < 12; ++j) {
      acc0[j] = cf.c[3*jb+1]*u0[j] + cf.c[3*jb+2]*w0[j];
      acc1[j] = cf.c[3*jb+1]*u1[j] + cf.c[3*jb+2]*w1[j];
    }
    add_diag(acc0, acc1, p, h, cf.c[3*jb]);
    mmtileH(&Lb[p*24], &Lb[(p+12)*24], La + c0, acc0, acc1);   // += P * u3
    if (jb > 0) {
      __syncthreads();                   // Lb(P-row) reads done
      st12(&Lb[p*24 + c0], acc0); st12(&Lb[(p+12)*24 + c0], acc1);
      __syncthreads();                   // Lb = newP
    } else {
      st12(io + mat*576 + p*24 + c0, acc0);
      st12(io + mat*576 + (p+12)*24 + c0, acc1);
    }
  }
}

// ---------- K4: congruence + Frobenius norm + 9-step Newton-Schulz sqrt ----------
// Retiled 4 rows x 12 cols (12 threads/matrix, MATS4=16/block): one B-read
// serves 4 output rows -> LDS wave-instr/(matrix*matmul) 31.5 -> 18 (the
// measured bottleneck). LDS 78336 B -> 2 blocks/CU; VGPR cap 256 via
// __launch_bounds__(192,2) (LDS binds occupancy, not VGPR). Per-element
// k-order identical to round 7; only the norm-reduction grouping changes
// (positive squares -> ~1 ulp in one scalar).
__global__ __launch_bounds__(BLK, 2) void k_csqrt(float* __restrict__ io,
                                                  const float* __restrict__ W) {
  __shared__ __align__(16) float lds[MATS4][2][LROW];  // 75264 B
  __shared__ __align__(16) float Wt[576];
  __shared__ float red[BLK];
  const int tid = threadIdx.x;
  const int lm = tid / 12, t12 = tid % 12, p = t12 >> 1, h = t12 & 1, c0 = h * 12;
  const long mat = (long)blockIdx.x * MATS4 + lm;
  float *La = lds[lm][0], *Lb = lds[lm][1];
  const int r0 = p, r1 = p + 6, r2 = p + 12, r3 = p + 18;

  for (int i = tid; i < 576; i += BLK) {
    const int k = i / 24, j = i % 24;
    Wt[i] = W[j*24 + k];
  }
  {
    float e[12];
    ld12(io + mat*576 + r0*24 + c0, e); st12(&La[r0*24 + c0], e);
    ld12(io + mat*576 + r1*24 + c0, e); st12(&La[r1*24 + c0], e);
    ld12(io + mat*576 + r2*24 + c0, e); st12(&La[r2*24 + c0], e);
    ld12(io + mat*576 + r3*24 + c0, e); st12(&La[r3*24 + c0], e);
  }
  __syncthreads();                                // La = E, Wt ready

  {
    float t0[12], t1[12], t2[12], t3[12];
    zero12(t0); zero12(t1); zero12(t2); zero12(t3);
    mmtile4(W + r0*24, W + r1*24, W + r2*24, W + r3*24, La + c0,
            t0, t1, t2, t3);                      // F = W * E
    st12(&Lb[r0*24 + c0], t0); st12(&Lb[r1*24 + c0], t1);
    st12(&Lb[r2*24 + c0], t2); st12(&Lb[r3*24 + c0], t3);
  }
  __syncthreads();                                // Lb = F; La(E) reads done

  {
    float t0[12], t1[12], t2[12], t3[12];
    zero12(t0); zero12(t1); zero12(t2); zero12(t3);
    mmtile4(&Lb[r0*24], &Lb[r1*24], &Lb[r2*24], &Lb[r3*24], Wt + c0,
            t0, t1, t2, t3);                      // C = F * W^T
    float s = 0.f;
#pragma unroll
    for (int j = 0; j < 12; ++j)
      s += t0[j]*t0[j] + t1[j]*t1[j] + t2[j]*t2[j] + t3[j]*t3[j];
    red[tid] = s;
    __syncthreads();                              // red ready; Lb(F-row) reads done
    float tot = 0.f;
#pragma unroll
    for (int q = 0; q < 12; ++q) tot += red[lm*12 + q];
    const float inv = 1.0f / sqrtf(tot);
#pragma unroll
    for (int j = 0; j < 12; ++j) { t0[j] *= inv; t1[j] *= inv; t2[j] *= inv; t3[j] *= inv; }
    st12(&La[r0*24 + c0], t0); st12(&La[r1*24 + c0], t1);
    st12(&La[r2*24 + c0], t2); st12(&La[r3*24 + c0], t3);
  }
  __syncthreads();                                // La = M0 (normalized)

  // ---- iter 0 (a=2, Y=M): newY(=MT) = 2M - M*M ; newM = 2*MT - MT*M
  {
    float m0[12], m1[12], m2[12], m3[12];
    zero12(m0); zero12(m1); zero12(m2); zero12(m3);
    mmtile4(&La[r0*24], &La[r1*24], &La[r2*24], &La[r3*24], La + c0,
            m0, m1, m2, m3);                      // M*M
    {
      float t[12];
      ld12(&La[r0*24 + c0], t);
#pragma unroll
      for (int j = 0; j < 12; ++j) m0[j] = 2.f*t[j] - m0[j];
      ld12(&La[r1*24 + c0], t);
#pragma unroll
      for (int j = 0; j < 12; ++j) m1[j] = 2.f*t[j] - m1[j];
      ld12(&La[r2*24 + c0], t);
#pragma unroll
      for (int j = 0; j < 12; ++j) m2[j] = 2.f*t[j] - m2[j];
      ld12(&La[r3*24 + c0], t);
#pragma unroll
      for (int j = 0; j < 12; ++j) m3[j] = 2.f*t[j] - m3[j];
    }
    st12(&Lb[r0*24 + c0], m0); st12(&Lb[r1*24 + c0], m1);
    st12(&Lb[r2*24 + c0], m2); st12(&Lb[r3*24 + c0], m3);  // Lb = MT (= Y)
    __syncthreads();
    float q0[12], q1[12], q2[12], q3[12];
    zero12(q0); zero12(q1); zero12(q2); zero12(q3);
    mmtile4(&Lb[r0*24], &Lb[r1*24], &Lb[r2*24], &Lb[r3*24], La + c0,
            q0, q1, q2, q3);                      // MT*M
    {
      float t[12];
      ld12(&Lb[r0*24 + c0], t);
#pragma unroll
      for (int j = 0; j < 12; ++j) q0[j] = 2.f*t[j] - q0[j];
      ld12(&Lb[r1*24 + c0], t);
#pragma unroll
      for (int j = 0; j < 12; ++j) q1[j] = 2.f*t[j] - q1[j];
      ld12(&Lb[r2*24 + c0], t);
#pragma unroll
      for (int j = 0; j < 12; ++j) q2[j] = 2.f*t[j] - q2[j];
      ld12(&Lb[r3*24 + c0], t);
#pragma unroll
      for (int j = 0; j < 12; ++j) q3[j] = 2.f*t[j] - q3[j];
    }
    __syncthreads();                              // La(M)/Lb(MT) reads done
    st12(&La[r0*24 + c0], q0); st12(&La[r1*24 + c0], q1);
    st12(&La[r2*24 + c0], q2); st12(&La[r3*24 + c0], q3);
    __syncthreads();                              // La = newM; Lb = Y
  }

  // ---- iters 1..7: {MT-phase, newY-phase, store MT, q-phase, store newY/newM}
#pragma unroll 1
  for (int it = 1; it < 8; ++it) {
    const float aa = (it < 6) ? 2.0f : 1.5f;
    const float am1 = aa - 1.0f;
    // MT = aa*M - am1*(M*M)
    float m0[12], m1[12], m2[12], m3[12];
    zero12(m0); zero12(m1); zero12(m2); zero12(m3);
    mmtile4(&La[r0*24], &La[r1*24], &La[r2*24], &La[r3*24], La + c0,
            m0, m1, m2, m3);
    {
      float t[12];
      ld12(&La[r0*24 + c0], t);
#pragma unroll
      for (int j = 0; j < 12; ++j) m0[j] = aa*t[j] - am1*m0[j];
      ld12(&La[r1*24 + c0], t);
#pragma unroll
      for (int j = 0; j < 12; ++j) m1[j] = aa*t[j] - am1*m1[j];
      ld12(&La[r2*24 + c0], t);
#pragma unroll
      for (int j = 0; j < 12; ++j) m2[j] = aa*t[j] - am1*m2[j];
      ld12(&La[r3*24 + c0], t);
#pragma unroll
      for (int j = 0; j < 12; ++j) m3[j] = aa*t[j] - am1*m3[j];
    }
    // newY = aa*Y - am1*(Y*M)
    float y0[12], y1[12], y2[12], y3[12];
    zero12(y0); zero12(y1); zero12(y2); zero12(y3);
    mmtile4(&Lb[r0*24], &Lb[r1*24], &Lb[r2*24], &Lb[r3*24], La + c0,
            y0, y1, y2, y3);
    {
      float t[12];
      ld12(&Lb[r0*24 + c0], t);
#pragma unroll
      for (int j = 0; j < 12; ++j) y0[j] = aa*t[j] - am1*y0[j];
      ld12(&Lb[r1*24 + c0], t);
#pragma unroll
      for (int j = 0; j < 12; ++j) y1[j] = aa*t[j] - am1*y1[j];
      ld12(&Lb[r2*24 + c0], t);
#pragma unroll
      for (int j = 0; j < 12; ++j) y2[j] = aa*t[j] - am1*y2[j];
      ld12(&Lb[r3*24 + c0], t);
#pragma unroll
      for (int j = 0; j < 12; ++j) y3[j] = aa*t[j] - am1*y3[j];
    }
    __syncthreads();                              // La(M)/Lb(Y) reads done
    st12(&Lb[r0*24 + c0], m0); st12(&Lb[r1*24 + c0], m1);
    st12(&Lb[r2*24 + c0], m2); st12(&Lb[r3*24 + c0], m3);  // Lb = MT
    __syncthreads();
    // newM = aa*MT - am1*(MT*M)
    float q0[12], q1[12], q2[12], q3[12];
    zero12(q0); zero12(q1); zero12(q2); zero12(q3);
    mmtile4(&Lb[r0*24], &Lb[r1*24], &Lb[r2*24], &Lb[r3*24], La + c0,
            q0, q1, q2, q3);
    {
      float t[12];
      ld12(&Lb[r0*24 + c0], t);
#pragma unroll
      for (int j = 0; j < 12; ++j) q0[j] = aa*t[j] - am1*q0[j];
      ld12(&Lb[r1*24 + c0], t);
#pragma unroll
      for (int j = 0; j < 12; ++j) q1[j] = aa*t[j] - am1*q1[j];
      ld12(&Lb[r2*24 + c0], t);
#pragma unroll
      for (int j = 0; j < 12; ++j) q2[j] = aa*t[j] - am1*q2[j];
      ld12(&Lb[r3*24 + c0], t);
#pragma unroll
      for (int j = 0; j < 12; ++j) q3[j] = aa*t[j] - am1*q3[j];
    }
    __syncthreads();                              // Lb(MT)/La(M) reads done
    st12(&Lb[r0*24 + c0], y0); st12(&Lb[r1*24 + c0], y1);
    st12(&Lb[r2*24 + c0], y2); st12(&Lb[r3*24 + c0], y3);  // Lb = newY
    st12(&La[r0*24 + c0], q0); st12(&La[r1*24 + c0], q1);
    st12(&La[r2*24 + c0], q2); st12(&La[r3*24 + c0], q3);  // La = newM
    __syncthreads();
  }

  // ---- iter 8 (a=1.5): final Y = 1.5*Y - 0.5*(Y*M)
  {
    float y0[12], y1[12], y2[12], y3[12];
    zero12(y0); zero12(y1); zero12(y2); zero12(y3);
    mmtile4(&Lb[r0*24], &Lb[r1*24], &Lb[r2*24], &Lb[r3*24], La + c0,
            y0, y1, y2, y3);
    float t[12];
    ld12(&Lb[r0*24 + c0], t);
#pragma unroll
    for (int j = 0; j < 12; ++j) y0[j] = 1.5f*t[j] - 0.5f*y0[j];
    ld12(&Lb[r1*24 + c0], t);
#pragma unroll
    for (int j = 0; j < 12; ++j) y1[j] = 1.5f*t[j] - 0.5f*y1[j];
    ld12(&Lb[r2*24 + c0], t);
#pragma unroll
    for (int j = 0; j < 12; ++j) y2[j] = 1.5f*t[j] - 0.5f*y2[j];
    ld12(&Lb[r3*24 + c0], t);
#pragma unroll
    for (int j = 0; j < 12; ++j) y3[j] = 1.5f*t[j] - 0.5f*y3[j];
    st12(io + mat*576 + r0*24 + c0, y0);
    st12(io + mat*576 + r1*24 + c0, y1);
    st12(io + mat*576 + r2*24 + c0, y2);
    st12(io + mat*576 + r3*24 + c0, y3);
  }
}

// ---------- host: Chebyshev interpolation -> monomial coefficients in u ----------
static void chebfit_host(double lo, double hi, int D, int islog, float* out) {
  const int N = 200;
  double a[32];
  for (int k = 0; k < 32; ++k) a[k] = 0.0;
  for (int i = 0; i < N; ++i) {
    double th = M_PI * (i + 0.5) / N;
    double u = cos(th);
    double xx = 0.5 * ((hi - lo) * u + (hi + lo));
    double f = islog ? log(xx) : exp(xx);
    for (int k = 0; k <= D; ++k) a[k] += f * cos(k * th);
  }
  for (int k = 0; k <= D; ++k) a[k] *= 2.0 / N;
  a[0] *= 0.5;
  double b[32], tp[32], tc[32], tn[32];
  for (int m = 0; m < 32; ++m) { b[m] = 0; tp[m] = 0; tc[m] = 0; tn[m] = 0; }
  tp[0] = 1.0; b[0] += a[0];
  tc[1] = 1.0; if (D >= 1) b[1] += a[1];
  for (int k = 2; k <= D; ++k) {
    for (int m = 0; m < 32; ++m) tn[m] = -tp[m];
    for (int m = 1; m < 32; ++m) tn[m] += 2.0 * tc[m-1];
    for (int m = 0; m <= k; ++m) b[m] += a[k] * tn[m];
    for (int m = 0; m < 32; ++m) { tp[m] = tc[m]; tc[m] = tn[m]; }
  }
  for (int m = 0; m < 32; ++m) out[m] = (float)b[m];
  out[30] = (float)(2.0 / (hi - lo));          // 1/d
  out[31] = (float)((hi + lo) / (hi - lo));    // c/d
}

extern "C" void kernel_launch(void* const* d_in, const int* in_sizes, int n_in,
                              void* d_out, int out_size, void* d_ws, size_t ws_size,
                              hipStream_t stream) {
  const float* x = (const float*)d_in[0];
  const float* A = (const float*)d_in[1];
  const float* W = (const float*)d_in[2];
  float* out = (float*)d_out;

  Coefs cl, ce;
  chebfit_host(0.47, 7.9, 23, 1, cl.c);   // log on the SPD input spectrum
  chebfit_host(-1.8, 3.9, 11, 0, ce.c);   // exp on the aggregated tangent spectrum

  k_logm <<<NMATS/MATS, BLK, 0, stream>>>(x, out, cl);
  k_agg  <<<NGROUPS,   256, 0, stream>>>(A, out);
  k_expm <<<NMATS/MATS, BLK, 0, stream>>>(out, ce);
  k_csqrt<<<NMATS/MATS4, BLK, 0, stream>>>(out, W);
}